// Round 8
// baseline (298.139 us; speedup 1.0000x reference)
//
#include <hip/hip_runtime.h>
#include <hip/hip_bf16.h>

typedef __attribute__((ext_vector_type(8))) __bf16 bf16x8;
typedef __attribute__((ext_vector_type(4))) float floatx4;

#define NVALID 3000
#define NPAD   3072
#define FEA    128
#define ZSPLIT 4
#define KCHUNK 768
#define PSTRIDE 393216   // NPAD*128
#define SLOT   ((size_t)ZSPLIT * PSTRIDE)

// async global->LDS, 16B per lane
__device__ __forceinline__ void gload16(const void* g, void* l) {
    __builtin_amdgcn_global_load_lds(
        (const __attribute__((address_space(1))) void*)g,
        (__attribute__((address_space(3))) void*)l,
        16, 0, 0);
}

__device__ __forceinline__ float b2f(__hip_bfloat16 h) { return __bfloat162float(h); }

// ---------------------------------------------------------------- fused 3-layer MLP (row-independent)
__global__ __launch_bounds__(256) void mlp_fused(
    const float* __restrict__ Xd, const float* __restrict__ Xp,
    const float* __restrict__ Wd1, const float* __restrict__ bd1,
    const float* __restrict__ Wd2, const float* __restrict__ bd2,
    const float* __restrict__ Wd3, const float* __restrict__ bd3,
    const float* __restrict__ Wp1, const float* __restrict__ bp1,
    const float* __restrict__ Wp2, const float* __restrict__ bp2,
    const float* __restrict__ Wp3, const float* __restrict__ bp3,
    float* __restrict__ Y)
{
    const bool isP = blockIdx.x >= 125;
    const float* X  = isP ? Xp : Xd;
    const float* W1 = isP ? Wp1 : Wd1; const float* b1 = isP ? bp1 : bd1;
    const float* W2 = isP ? Wp2 : Wd2; const float* b2 = isP ? bp2 : bd2;
    const float* W3 = isP ? Wp3 : Wd3; const float* b3 = isP ? bp3 : bd3;
    const int m0loc = (isP ? (blockIdx.x - 125) : blockIdx.x) * 8;
    const int m0out = blockIdx.x * 8;

    __shared__ float S0[8][128], S1[8][128];
    const int t = threadIdx.x;
    for (int s2 = t; s2 < 1024; s2 += 256) {
        int r = s2 >> 7, ii = s2 & 127;
        S0[r][ii] = X[(size_t)(m0loc + r) * 128 + ii];
    }
    __syncthreads();
    const int o = t & 127, rh = t >> 7;

    {
        float a0 = 0.f, a1 = 0.f, a2 = 0.f, a3 = 0.f;
        const float* wr = W1 + (size_t)o * 128;
        for (int i = 0; i < 128; ++i) {
            float w = wr[i];
            a0 += S0[rh + 0][i] * w; a1 += S0[rh + 2][i] * w;
            a2 += S0[rh + 4][i] * w; a3 += S0[rh + 6][i] * w;
        }
        float bo = b1[o];
        S1[rh + 0][o] = fmaxf(a0 + bo, 0.f);
        S1[rh + 2][o] = fmaxf(a1 + bo, 0.f);
        S1[rh + 4][o] = fmaxf(a2 + bo, 0.f);
        S1[rh + 6][o] = fmaxf(a3 + bo, 0.f);
    }
    __syncthreads();
    {
        float a0 = 0.f, a1 = 0.f, a2 = 0.f, a3 = 0.f;
        const float* wr = W2 + (size_t)o * 128;
        for (int i = 0; i < 128; ++i) {
            float w = wr[i];
            a0 += S1[rh + 0][i] * w; a1 += S1[rh + 2][i] * w;
            a2 += S1[rh + 4][i] * w; a3 += S1[rh + 6][i] * w;
        }
        float bo = b2[o];
        S0[rh + 0][o] = fmaxf(a0 + bo, 0.f);
        S0[rh + 2][o] = fmaxf(a1 + bo, 0.f);
        S0[rh + 4][o] = fmaxf(a2 + bo, 0.f);
        S0[rh + 6][o] = fmaxf(a3 + bo, 0.f);
    }
    __syncthreads();
    {
        float a0 = 0.f, a1 = 0.f, a2 = 0.f, a3 = 0.f;
        const float* wr = W3 + (size_t)o * 128;
        for (int i = 0; i < 128; ++i) {
            float w = wr[i];
            a0 += S0[rh + 0][i] * w; a1 += S0[rh + 2][i] * w;
            a2 += S0[rh + 4][i] * w; a3 += S0[rh + 6][i] * w;
        }
        float bo = b3[o];
        Y[(size_t)(m0out + rh + 0) * 128 + o] = fmaxf(a0 + bo, 0.f);
        Y[(size_t)(m0out + rh + 2) * 128 + o] = fmaxf(a1 + bo, 0.f);
        Y[(size_t)(m0out + rh + 4) * 128 + o] = fmaxf(a2 + bo, 0.f);
        Y[(size_t)(m0out + rh + 6) * 128 + o] = fmaxf(a3 + bo, 0.f);
    }
}

// ---------------------------------------------------------------- softmax5
__device__ __forceinline__ void softmax5(const float* __restrict__ w, float* s)
{
    float m = w[0];
    #pragma unroll
    for (int e = 1; e < 5; ++e) m = fmaxf(m, w[e]);
    float sum = 0.f;
    #pragma unroll
    for (int e = 0; e < 5; ++e) { s[e] = __expf(w[e] - m); sum += s[e]; }
    float r = 1.f / sum;
    #pragma unroll
    for (int e = 0; e < 5; ++e) s[e] *= r;
}

// ---------------------------------------------------------------- gtconv: one full row per block (384 thr x 8 cols)
// fused: row sums of b00,g10,b01,g11 -> r1v[4][NPAD]
__global__ __launch_bounds__(384) void gtconv_fused(
    const float* __restrict__ A, const float* __restrict__ w0a,
    const float* __restrict__ w0b, const float* __restrict__ w1,
    __hip_bfloat16* __restrict__ a00, __hip_bfloat16* __restrict__ b00,
    __hip_bfloat16* __restrict__ g10,
    __hip_bfloat16* __restrict__ a01, __hip_bfloat16* __restrict__ b01,
    __hip_bfloat16* __restrict__ g11,
    float* __restrict__ r1v)
{
    float sw[6][5];
    softmax5(w0a + 0, sw[0]); softmax5(w0b + 0, sw[1]); softmax5(w1 + 0, sw[2]);
    softmax5(w0a + 5, sw[3]); softmax5(w0b + 5, sw[4]); softmax5(w1 + 5, sw[5]);

    const int i  = blockIdx.x;
    const int t  = threadIdx.x;
    const int j0 = t * 8;                 // 3000 = 375*8: threads >=375 are all-pad
    float acc[6][8] = {};
    if (i < NVALID && j0 < NVALID) {
        #pragma unroll
        for (int e = 0; e < 5; ++e) {
            const float* Ae = A + (size_t)e * 9000000 + (size_t)i * 3000 + j0;
            float4 v0 = *reinterpret_cast<const float4*>(Ae);
            float4 v1 = *reinterpret_cast<const float4*>(Ae + 4);
            float x[8] = { v0.x, v0.y, v0.z, v0.w, v1.x, v1.y, v1.z, v1.w };
            #pragma unroll
            for (int m = 0; m < 6; ++m) {
                float se = sw[m][e];
                #pragma unroll
                for (int u = 0; u < 8; ++u) acc[m][u] += se * x[u];
            }
        }
    }
    __hip_bfloat16* dsts[6] = { a00, b00, g10, a01, b01, g11 };
    const size_t base = (size_t)i * NPAD + j0;
    float rs[4];  // rounded row-sums of b00,g10,b01,g11
    #pragma unroll
    for (int m = 0; m < 6; ++m) {
        __align__(16) __hip_bfloat16 h[8];
        float s = 0.f;
        #pragma unroll
        for (int u = 0; u < 8; ++u) {
            h[u] = __float2bfloat16(acc[m][u]);
            s += b2f(h[u]);
        }
        *reinterpret_cast<uint4*>(&dsts[m][base]) = *reinterpret_cast<const uint4*>(h);
        if (m == 1) rs[0] = s; else if (m == 2) rs[1] = s;
        else if (m == 4) rs[2] = s; else if (m == 5) rs[3] = s;
    }
    // block reduce rs[0..3] over 384 threads (6 waves)
    __shared__ float red[6][4];
    #pragma unroll
    for (int q = 0; q < 4; ++q) {
        float s = rs[q];
        #pragma unroll
        for (int off = 32; off > 0; off >>= 1) s += __shfl_down(s, off);
        if ((t & 63) == 0) red[t >> 6][q] = s;
    }
    __syncthreads();
    if (t == 0) {
        #pragma unroll
        for (int q = 0; q < 4; ++q) {
            float s = red[0][q] + red[1][q] + red[2][q]
                    + red[3][q] + red[4][q] + red[5][q];
            r1v[(size_t)q * NPAD + i] = s;
        }
    }
}

// ---------------------------------------------------------------- batched degree matvecs
// stage A (grid (NPAD,4)): y=0/1: dinv_c = 1/(a0_c . r1b_c + 1); y=2/3: mv1_c = b0_c . r1g_c
__global__ __launch_bounds__(256) void matvec_degA(
    const __hip_bfloat16* __restrict__ a0_0, const __hip_bfloat16* __restrict__ a0_1,
    const __hip_bfloat16* __restrict__ b0_0, const __hip_bfloat16* __restrict__ b0_1,
    const float* __restrict__ r1v,
    float* __restrict__ dinv2, float* __restrict__ mv12)
{
    const int y = blockIdx.y;
    const __hip_bfloat16* M = (y == 0) ? a0_0 : (y == 1) ? a0_1 : (y == 2) ? b0_0 : b0_1;
    const float* v = (y == 0) ? r1v : (y == 1) ? r1v + 2 * NPAD
                   : (y == 2) ? r1v + NPAD : r1v + 3 * NPAD;
    const size_t i = blockIdx.x;
    const int t = threadIdx.x;
    const __hip_bfloat16* row = M + i * NPAD;
    float s = 0.f;
    for (int k = t * 8; k < NPAD; k += 2048) {
        uint4 u = *reinterpret_cast<const uint4*>(&row[k]);
        const unsigned short* us = reinterpret_cast<const unsigned short*>(&u);
        #pragma unroll
        for (int e = 0; e < 8; ++e)
            s += __uint_as_float(((unsigned int)us[e]) << 16) * v[k + e];
    }
    #pragma unroll
    for (int off = 32; off > 0; off >>= 1) s += __shfl_down(s, off);
    __shared__ float red[4];
    if ((t & 63) == 0) red[t >> 6] = s;
    __syncthreads();
    if (t == 0) {
        float tot = red[0] + red[1] + red[2] + red[3];
        if (y < 2) dinv2[(size_t)y * NPAD + i] = 1.f / (tot + 1.f);
        else       mv12[(size_t)(y - 2) * NPAD + i] = tot;
    }
}

// stage B (grid (NPAD,2)): rsv_c = rsqrt(dinv_c*(a0_c . mv1_c + r1g_c) + 2)
__global__ __launch_bounds__(256) void matvec_degB(
    const __hip_bfloat16* __restrict__ a0_0, const __hip_bfloat16* __restrict__ a0_1,
    const float* __restrict__ mv12, const float* __restrict__ dinv2,
    const float* __restrict__ r1v, float* __restrict__ rsv2)
{
    const int c = blockIdx.y;
    const __hip_bfloat16* M = c ? a0_1 : a0_0;
    const float* v = mv12 + (size_t)c * NPAD;
    const float* add = r1v + (size_t)(2 * c + 1) * NPAD;
    const size_t i = blockIdx.x;
    const int t = threadIdx.x;
    const __hip_bfloat16* row = M + i * NPAD;
    float s = 0.f;
    for (int k = t * 8; k < NPAD; k += 2048) {
        uint4 u = *reinterpret_cast<const uint4*>(&row[k]);
        const unsigned short* us = reinterpret_cast<const unsigned short*>(&u);
        #pragma unroll
        for (int e = 0; e < 8; ++e)
            s += __uint_as_float(((unsigned int)us[e]) << 16) * v[k + e];
    }
    #pragma unroll
    for (int off = 32; off > 0; off >>= 1) s += __shfl_down(s, off);
    __shared__ float red[4];
    if ((t & 63) == 0) red[t >> 6] = s;
    __syncthreads();
    if (t == 0) {
        float tot = red[0] + red[1] + red[2] + red[3];
        rsv2[(size_t)c * NPAD + i] =
            rsqrtf(dinv2[(size_t)c * NPAD + i] * (tot + add[i]) + 2.f);
    }
}

// ---------------------------------------------------------------- DTI degree + scale (f32)
__global__ __launch_bounds__(256) void rowdeg_f32(
    const float* __restrict__ src, float* __restrict__ outv)
{
    const int i = blockIdx.x, t = threadIdx.x;
    float s = 0.f;
    if (i < NVALID) {
        const float* row = src + (size_t)i * 3000;
        for (int j4 = t; j4 < 750; j4 += 256) {
            float4 v = *reinterpret_cast<const float4*>(row + j4 * 4);
            s += v.x + v.y + v.z + v.w;
        }
    }
    #pragma unroll
    for (int off = 32; off > 0; off >>= 1) s += __shfl_down(s, off);
    __shared__ float red[4];
    if ((t & 63) == 0) red[t >> 6] = s;
    __syncthreads();
    if (t == 0) {
        float tot = red[0] + red[1] + red[2] + red[3];
        outv[i] = rsqrtf(tot + 2.f);
    }
}

__global__ __launch_bounds__(256) void scale_cast_f32(
    const float* __restrict__ src, int lds_, int nvalid,
    const float* __restrict__ vec, __hip_bfloat16* __restrict__ dst)
{
    const int i = blockIdx.y;
    const int j0 = (blockIdx.x * 256 + threadIdx.x) * 4;
    const float vi = vec[i];
    float v[4];
    if (i < nvalid && j0 + 3 < nvalid) {
        float4 f = *reinterpret_cast<const float4*>(src + (size_t)i * lds_ + j0);
        v[0] = f.x; v[1] = f.y; v[2] = f.z; v[3] = f.w;
    } else {
        #pragma unroll
        for (int u = 0; u < 4; ++u) {
            int j = j0 + u;
            v[u] = (i < nvalid && j < nvalid) ? src[(size_t)i * lds_ + j] : 0.f;
        }
    }
    #pragma unroll
    for (int u = 0; u < 4; ++u) {
        int j = j0 + u;
        if (j == i && i < nvalid) v[u] += 2.f;
        v[u] *= vi * vec[j];
    }
    __align__(8) __hip_bfloat16 h[4];
    #pragma unroll
    for (int u = 0; u < 4; ++u) h[u] = __float2bfloat16(v[u]);
    *reinterpret_cast<uint2*>(&dst[(size_t)i * NPAD + j0]) =
        *reinterpret_cast<const uint2*>(h);
}

// ---------------------------------------------------------------- transpose feature (f32 -> bf16^T)
__global__ __launch_bounds__(256) void transpose_feat(
    const float* __restrict__ X, int nvalid, __hip_bfloat16* __restrict__ XT)
{
    __shared__ float Ts[32][33];
    const int k0 = blockIdx.x * 32, n0 = blockIdx.y * 32;
    const int t = threadIdx.x, tr = t >> 5, tc = t & 31;
    #pragma unroll
    for (int p = 0; p < 4; ++p) {
        int k = k0 + tr + p * 8;
        Ts[tr + p * 8][tc] = (k < nvalid) ? X[(size_t)k * 128 + n0 + tc] : 0.f;
    }
    __syncthreads();
    #pragma unroll
    for (int p = 0; p < 4; ++p) {
        int n = tr + p * 8;
        XT[(size_t)(n0 + n) * NPAD + k0 + tc] = __float2bfloat16(Ts[tc][n]);
    }
}

// ---------------------------------------------------------------- scale columns of XT by rsv_c -> W0T_c
__global__ __launch_bounds__(256) void scale_colsT2(
    const __hip_bfloat16* __restrict__ XT, const float* __restrict__ rsv2,
    __hip_bfloat16* __restrict__ W0T_0, __hip_bfloat16* __restrict__ W0T_1)
{
    const int c = blockIdx.z;
    const float* s = rsv2 + (size_t)c * NPAD;
    __hip_bfloat16* W0T = c ? W0T_1 : W0T_0;
    const int f = blockIdx.y;
    const int k0 = (blockIdx.x * 256 + threadIdx.x) * 8;
    if (k0 >= NPAD) return;
    uint4 u = *reinterpret_cast<const uint4*>(&XT[(size_t)f * NPAD + k0]);
    const unsigned short* us = reinterpret_cast<const unsigned short*>(&u);
    __align__(16) __hip_bfloat16 h[8];
    #pragma unroll
    for (int e = 0; e < 8; ++e) {
        float x = __uint_as_float(((unsigned int)us[e]) << 16);
        h[e] = __float2bfloat16(x * s[k0 + e]);
    }
    *reinterpret_cast<uint4*>(&W0T[(size_t)f * NPAD + k0]) =
        *reinterpret_cast<const uint4*>(h);
}

// ---------------------------------------------------------------- batched thin GEMM (up to 3 A/B pairs)
// grid (1, 24, NB*ZSPLIT); b = z/ZSPLIT; writes f32 partials at slot b.
__global__ __launch_bounds__(256, 3) void gemm_bt_batch(
    const __hip_bfloat16* __restrict__ A0, const __hip_bfloat16* __restrict__ B0,
    const __hip_bfloat16* __restrict__ A1, const __hip_bfloat16* __restrict__ B1,
    const __hip_bfloat16* __restrict__ A2, const __hip_bfloat16* __restrict__ B2,
    float* __restrict__ part)
{
    const int b  = blockIdx.z / ZSPLIT;
    const int zz = blockIdx.z % ZSPLIT;
    const __hip_bfloat16* A  = (b == 0) ? A0 : (b == 1) ? A1 : A2;
    const __hip_bfloat16* BT = (b == 0) ? B0 : (b == 1) ? B1 : B2;
    float* C = part + (size_t)b * SLOT + (size_t)zz * PSTRIDE;

    __shared__ __align__(16) __hip_bfloat16 As[128 * 32];
    __shared__ __align__(16) __hip_bfloat16 Bs[128 * 32];
    const int t = threadIdx.x;
    const int lane = t & 63;
    const int w = t >> 6;
    const int wm = w >> 1, wn = w & 1;
    const int tm = blockIdx.y;
    const int kbeg = zz * KCHUNK;

    const int srow = lane >> 2;
    const int skg  = (lane & 3) * 8;
    const __hip_bfloat16* Ag = A  + (size_t)(tm * 128 + w * 32 + srow) * NPAD + skg;
    const __hip_bfloat16* Bg = BT + (size_t)(w * 32 + srow) * NPAD + skg;
    __hip_bfloat16* Al0 = &As[w * 1024];
    __hip_bfloat16* Al1 = &As[w * 1024 + 512];
    __hip_bfloat16* Bl0 = &Bs[w * 1024];
    __hip_bfloat16* Bl1 = &Bs[w * 1024 + 512];

    floatx4 acc[4][4] = {};

    for (int k0 = kbeg; k0 < kbeg + KCHUNK; k0 += 32) {
        __syncthreads();
        gload16(Ag + k0,             Al0);
        gload16(Ag + 16 * NPAD + k0, Al1);
        gload16(Bg + k0,             Bl0);
        gload16(Bg + 16 * NPAD + k0, Bl1);
        __syncthreads();

        bf16x8 af[4], bfv[4];
        const int koff = (lane >> 4) * 8;
        #pragma unroll
        for (int mi = 0; mi < 4; ++mi)
            af[mi] = *reinterpret_cast<const bf16x8*>(
                &As[(wm * 64 + mi * 16 + (lane & 15)) * 32 + koff]);
        #pragma unroll
        for (int ni = 0; ni < 4; ++ni)
            bfv[ni] = *reinterpret_cast<const bf16x8*>(
                &Bs[(wn * 64 + ni * 16 + (lane & 15)) * 32 + koff]);
        #pragma unroll
        for (int mi = 0; mi < 4; ++mi)
            #pragma unroll
            for (int ni = 0; ni < 4; ++ni)
                acc[mi][ni] = __builtin_amdgcn_mfma_f32_16x16x32_bf16(
                    af[mi], bfv[ni], acc[mi][ni], 0, 0, 0);
    }

    const int r0 = tm * 128 + wm * 64 + ((lane >> 4) << 2);
    const int c0 = wn * 64 + (lane & 15);
    #pragma unroll
    for (int mi = 0; mi < 4; ++mi)
        #pragma unroll
        for (int ni = 0; ni < 4; ++ni)
            #pragma unroll
            for (int r = 0; r < 4; ++r)
                C[(size_t)(r0 + mi * 16 + r) * 128 + c0 + ni * 16] = acc[mi][ni][r];
}

// ---------------------------------------------------------------- final GEMM (sigmoid epilogue)
__global__ __launch_bounds__(256, 3) void gemm_sig(
    const __hip_bfloat16* __restrict__ A, const __hip_bfloat16* __restrict__ BT,
    float* __restrict__ C, int Kchunk, int lda, int ldb, int ldc,
    int Mvalid, int Nvalid)
{
    __shared__ __align__(16) __hip_bfloat16 As[128 * 32];
    __shared__ __align__(16) __hip_bfloat16 Bs[128 * 32];
    const int t = threadIdx.x;
    const int lane = t & 63;
    const int w = t >> 6;
    const int wm = w >> 1, wn = w & 1;
    const int tm = blockIdx.y, tn = blockIdx.x;

    const int srow = lane >> 2;
    const int skg  = (lane & 3) * 8;
    const __hip_bfloat16* Ag = A  + (size_t)(tm * 128 + w * 32 + srow) * lda + skg;
    const __hip_bfloat16* Bg = BT + (size_t)(tn * 128 + w * 32 + srow) * ldb + skg;
    __hip_bfloat16* Al0 = &As[w * 1024];
    __hip_bfloat16* Al1 = &As[w * 1024 + 512];
    __hip_bfloat16* Bl0 = &Bs[w * 1024];
    __hip_bfloat16* Bl1 = &Bs[w * 1024 + 512];

    floatx4 acc[4][4] = {};

    for (int k0 = 0; k0 < Kchunk; k0 += 32) {
        __syncthreads();
        gload16(Ag + k0,            Al0);
        gload16(Ag + 16 * lda + k0, Al1);
        gload16(Bg + k0,            Bl0);
        gload16(Bg + 16 * ldb + k0, Bl1);
        __syncthreads();

        bf16x8 af[4], bfv[4];
        const int koff = (lane >> 4) * 8;
        #pragma unroll
        for (int mi = 0; mi < 4; ++mi)
            af[mi] = *reinterpret_cast<const bf16x8*>(
                &As[(wm * 64 + mi * 16 + (lane & 15)) * 32 + koff]);
        #pragma unroll
        for (int ni = 0; ni < 4; ++ni)
            bfv[ni] = *reinterpret_cast<const bf16x8*>(
                &Bs[(wn * 64 + ni * 16 + (lane & 15)) * 32 + koff]);
        #pragma unroll
        for (int mi = 0; mi < 4; ++mi)
            #pragma unroll
            for (int ni = 0; ni < 4; ++ni)
                acc[mi][ni] = __builtin_amdgcn_mfma_f32_16x16x32_bf16(
                    af[mi], bfv[ni], acc[mi][ni], 0, 0, 0);
    }

    const int r0 = tm * 128 + wm * 64 + ((lane >> 4) << 2);
    const int c0 = tn * 128 + wn * 64 + (lane & 15);
    #pragma unroll
    for (int mi = 0; mi < 4; ++mi)
        #pragma unroll
        for (int ni = 0; ni < 4; ++ni) {
            const int col = c0 + ni * 16;
            #pragma unroll
            for (int r = 0; r < 4; ++r) {
                const int row = r0 + mi * 16 + r;
                if (row < Mvalid && col < Nvalid)
                    C[(size_t)row * ldc + col] =
                        1.f / (1.f + __expf(-acc[mi][ni][r]));
            }
        }
}

// ---------------------------------------------------------------- batched K-split reduce + transpose
// grid (96, 4, NB). For b==0 with conv!=nullptr: DTI attention write (no transpose).
__global__ __launch_bounds__(256) void reduce_trans_b(
    const float* __restrict__ part,
    __hip_bfloat16* __restrict__ X0, __hip_bfloat16* __restrict__ X1,
    __hip_bfloat16* __restrict__ X2,
    __hip_bfloat16* __restrict__ R0, __hip_bfloat16* __restrict__ R1,
    __hip_bfloat16* __restrict__ R2,
    const float* __restrict__ ap, float* __restrict__ conv)
{
    const int b = blockIdx.z;
    const float* Pp = part + (size_t)b * SLOT;
    const int k0 = blockIdx.x * 32, n0 = blockIdx.y * 32;
    const int t = threadIdx.x, tr = t >> 5, tc = t & 31;

    if (b == 0 && conv != nullptr) {
        // DTI: conv[i*128+f] = att0 * sum_z
        float a0 = ap[0], a1 = ap[1], a2 = ap[2];
        float m = fmaxf(a0, fmaxf(a1, a2));
        float e0 = __expf(a0 - m), e1 = __expf(a1 - m), e2 = __expf(a2 - m);
        float att0 = e0 / (e0 + e1 + e2);
        #pragma unroll
        for (int p = 0; p < 4; ++p) {
            int i = k0 + tr + p * 8;
            float s = 0.f;
            #pragma unroll
            for (int z = 0; z < ZSPLIT; ++z)
                s += Pp[(size_t)z * PSTRIDE + (size_t)i * 128 + n0 + tc];
            conv[(size_t)i * 128 + n0 + tc] = att0 * s;
        }
        return;
    }

    __hip_bfloat16* XT = (b == 0) ? X0 : (b == 1) ? X1 : X2;
    __hip_bfloat16* Rm = (b == 0) ? R0 : (b == 1) ? R1 : R2;
    __shared__ float Ts[32][33];
    #pragma unroll
    for (int p = 0; p < 4; ++p) {
        int i = k0 + tr + p * 8;
        float s = 0.f;
        #pragma unroll
        for (int z = 0; z < ZSPLIT; ++z)
            s += Pp[(size_t)z * PSTRIDE + (size_t)i * 128 + n0 + tc];
        Ts[tr + p * 8][tc] = s;
        if (Rm) Rm[(size_t)i * 128 + n0 + tc] = __float2bfloat16(s);
    }
    __syncthreads();
    #pragma unroll
    for (int p = 0; p < 4; ++p) {
        int n = tr + p * 8;
        XT[(size_t)(n0 + n) * NPAD + k0 + tc] = __float2bfloat16(Ts[tc][n]);
    }
}

// ---------------------------------------------------------------- batched hop1 combine (grid (96,4,2))
__global__ __launch_bounds__(256) void combine_mid2(
    const float* __restrict__ part,
    const __hip_bfloat16* __restrict__ Zrm0, const __hip_bfloat16* __restrict__ Zrm1,
    const float* __restrict__ X,
    const float* __restrict__ rsv2, const float* __restrict__ dinv2,
    __hip_bfloat16* __restrict__ WpT0, __hip_bfloat16* __restrict__ WpT1,
    __hip_bfloat16* __restrict__ Wprm0, __hip_bfloat16* __restrict__ Wprm1)
{
    const int c = blockIdx.z;
    const float* Vp = part + (size_t)c * SLOT;
    const __hip_bfloat16* Zrm = c ? Zrm1 : Zrm0;
    const float* sv = rsv2 + (size_t)c * NPAD;
    const float* dv = dinv2 + (size_t)c * NPAD;
    __hip_bfloat16* WpT  = c ? WpT1 : WpT0;
    __hip_bfloat16* Wprm = c ? Wprm1 : Wprm0;

    __shared__ float Ts[32][33];
    const int k0 = blockIdx.x * 32, n0 = blockIdx.y * 32;
    const int t = threadIdx.x, tr = t >> 5, tc = t & 31;
    #pragma unroll
    for (int p = 0; p < 4; ++p) {
        int i = k0 + tr + p * 8;
        int f = n0 + tc;
        float vsum = b2f(Zrm[(size_t)i * 128 + f]);
        #pragma unroll
        for (int z = 0; z < ZSPLIT; ++z)
            vsum += Vp[(size_t)z * PSTRIDE + (size_t)i * 128 + f];
        float x  = (i < NVALID) ? X[(size_t)i * 128 + f] : 0.f;
        float si = sv[i];
        float out1 = si * dv[i] * vsum + 2.f * si * si * x;
        float wv = si * out1;
        Ts[tr + p * 8][tc] = wv;
        Wprm[(size_t)i * 128 + f] = __float2bfloat16(wv);
    }
    __syncthreads();
    #pragma unroll
    for (int p = 0; p < 4; ++p) {
        int n = tr + p * 8;
        WpT[(size_t)(n0 + n) * NPAD + k0 + tc] = __float2bfloat16(Ts[tc][n]);
    }
}

// ---------------------------------------------------------------- hop2 combine + attention for BOTH channels
__global__ __launch_bounds__(256) void combine_att2(
    const float* __restrict__ part,
    const __hip_bfloat16* __restrict__ Zrm0, const __hip_bfloat16* __restrict__ Zrm1,
    const __hip_bfloat16* __restrict__ Wprm0, const __hip_bfloat16* __restrict__ Wprm1,
    const float* __restrict__ rsv2, const float* __restrict__ dinv2,
    const float* __restrict__ ap, float* __restrict__ conv)
{
    const int idx = blockIdx.x * 256 + threadIdx.x;  // grid 1500 -> 3000*128
    const int i = idx >> 7;
    float v0 = b2f(Zrm0[idx]);
    float v1 = b2f(Zrm1[idx]);
    #pragma unroll
    for (int z = 0; z < ZSPLIT; ++z) {
        v0 += part[(size_t)z * PSTRIDE + idx];
        v1 += part[SLOT + (size_t)z * PSTRIDE + idx];
    }
    float s0 = rsv2[i],        d0 = dinv2[i];
    float s1 = rsv2[NPAD + i], d1 = dinv2[NPAD + i];
    float o0 = s0 * d0 * v0 + 2.f * s0 * b2f(Wprm0[idx]);
    float o1 = s1 * d1 * v1 + 2.f * s1 * b2f(Wprm1[idx]);
    float a0 = ap[0], a1 = ap[1], a2 = ap[2];
    float m = fmaxf(a0, fmaxf(a1, a2));
    float e0 = __expf(a0 - m), e1 = __expf(a1 - m), e2 = __expf(a2 - m);
    float inv = 1.f / (e0 + e1 + e2);
    conv[idx] += (e1 * inv) * o0 + (e2 * inv) * o1;
}

// ---------------------------------------------------------------- final split+cast
__global__ __launch_bounds__(256) void cast_split(
    const float* __restrict__ acc, __hip_bfloat16* __restrict__ dF,
    __hip_bfloat16* __restrict__ pF)
{
    const int idx = blockIdx.x * 256 + threadIdx.x;
    if (idx < 1024 * 128) {
        int r = idx >> 7;
        dF[idx] = __float2bfloat16(r < 1000 ? acc[idx] : 0.f);
    } else {
        int j = idx - 1024 * 128;
        int r = j >> 7;
        pF[j] = __float2bfloat16(r < 2000 ? acc[(size_t)(1000 + r) * 128 + (j & 127)] : 0.f);
    }
}

// ================================================================ launch
extern "C" void kernel_launch(void* const* d_in, const int* in_sizes, int n_in,
                              void* d_out, int out_size, void* d_ws, size_t ws_size,
                              hipStream_t stream)
{
    const float* A     = (const float*)d_in[0];
    const float* DTI   = (const float*)d_in[1];
    const float* drugS = (const float*)d_in[2];
    const float* protS = (const float*)d_in[3];
    const float* w0a   = (const float*)d_in[4];
    const float* w0b   = (const float*)d_in[5];
    const float* w1g   = (const float*)d_in[6];
    const float* ap    = (const float*)d_in[7];
    const float* wd1 = (const float*)d_in[10]; const float* bd1 = (const float*)d_in[11];
    const float* wd2 = (const float*)d_in[12]; const float* bd2 = (const float*)d_in[13];
    const float* wd3 = (const float*)d_in[14]; const float* bd3 = (const float*)d_in[15];
    const float* wp1 = (const float*)d_in[16]; const float* bp1 = (const float*)d_in[17];
    const float* wp2 = (const float*)d_in[18]; const float* bp2 = (const float*)d_in[19];
    const float* wp3 = (const float*)d_in[20]; const float* bp3 = (const float*)d_in[21];
    float* out = (float*)d_out;

    const size_t SQ_BF  = (size_t)NPAD * NPAD * 2;
    const size_t PAN_BF = (size_t)128 * NPAD * 2;
    char* p = (char*)d_ws;
    auto alloc = [&](size_t sz) { char* r = p; p += (sz + 255) & ~(size_t)255; return r; };
    __hip_bfloat16* sdti = (__hip_bfloat16*)alloc(SQ_BF);
    __hip_bfloat16* a0c[2], *b0c[2], *g1c[2];
    for (int c = 0; c < 2; ++c) {
        a0c[c] = (__hip_bfloat16*)alloc(SQ_BF);
        b0c[c] = (__hip_bfloat16*)alloc(SQ_BF);
        g1c[c] = (__hip_bfloat16*)alloc(SQ_BF);
    }
    float* part  = (float*)alloc((size_t)3 * SLOT * 4);
    float* r1v   = (float*)alloc((size_t)4 * NPAD * 4);
    float* dinv2 = (float*)alloc((size_t)2 * NPAD * 4);
    float* mv12  = (float*)alloc((size_t)2 * NPAD * 4);
    float* rsv2  = (float*)alloc((size_t)2 * NPAD * 4);
    float* degv  = (float*)alloc((size_t)NPAD * 4);
    float* fb    = (float*)alloc((size_t)NPAD * 128 * 4);
    float* conv  = (float*)alloc((size_t)NPAD * 128 * 4);
    __hip_bfloat16* XTF  = (__hip_bfloat16*)alloc(PAN_BF);
    __hip_bfloat16* XT2  = (__hip_bfloat16*)alloc(PAN_BF);
    __hip_bfloat16* W0T_0 = (__hip_bfloat16*)alloc(PAN_BF);
    __hip_bfloat16* W0T_1 = (__hip_bfloat16*)alloc(PAN_BF);
    __hip_bfloat16* ZT_0  = (__hip_bfloat16*)alloc(PAN_BF);
    __hip_bfloat16* ZT_1  = (__hip_bfloat16*)alloc(PAN_BF);
    __hip_bfloat16* Zrm_0 = (__hip_bfloat16*)alloc(PAN_BF);
    __hip_bfloat16* Zrm_1 = (__hip_bfloat16*)alloc(PAN_BF);
    __hip_bfloat16* UT_0  = (__hip_bfloat16*)alloc(PAN_BF);
    __hip_bfloat16* UT_1  = (__hip_bfloat16*)alloc(PAN_BF);
    __hip_bfloat16* WpT_0 = (__hip_bfloat16*)alloc(PAN_BF);
    __hip_bfloat16* WpT_1 = (__hip_bfloat16*)alloc(PAN_BF);
    __hip_bfloat16* Wprm_0 = (__hip_bfloat16*)alloc(PAN_BF);
    __hip_bfloat16* Wprm_1 = (__hip_bfloat16*)alloc(PAN_BF);
    __hip_bfloat16* dF = (__hip_bfloat16*)alloc((size_t)1024 * 128 * 2);
    __hip_bfloat16* pF = (__hip_bfloat16*)alloc((size_t)2048 * 128 * 2);
    if ((size_t)(p - (char*)d_ws) > ws_size) return;  // fail loud if ws too small

    // ---- fused MLPs -> fb; transpose
    mlp_fused<<<375, 256, 0, stream>>>(drugS, protS,
        wd1, bd1, wd2, bd2, wd3, bd3, wp1, bp1, wp2, bp2, wp3, bp3, fb);
    transpose_feat<<<dim3(96, 4), 256, 0, stream>>>(fb, 3000, XTF);

    // ---- gtconv (full-row blocks, fused rowsums)
    gtconv_fused<<<NPAD, 384, 0, stream>>>(A, w0a, w0b, w1g,
        a0c[0], b0c[0], g1c[0], a0c[1], b0c[1], g1c[1], r1v);

    // ---- DTI normalize
    rowdeg_f32<<<NPAD, 256, 0, stream>>>(DTI, degv);
    scale_cast_f32<<<dim3(3, NPAD), 256, 0, stream>>>(DTI, 3000, 3000, degv, sdti);

    // ---- batched degree matvecs + W0T
    matvec_degA<<<dim3(NPAD, 4), 256, 0, stream>>>(a0c[0], a0c[1], b0c[0], b0c[1],
        r1v, dinv2, mv12);
    matvec_degB<<<dim3(NPAD, 2), 256, 0, stream>>>(a0c[0], a0c[1], mv12, dinv2, r1v, rsv2);
    scale_colsT2<<<dim3(2, 128, 2), 256, 0, stream>>>(XTF, rsv2, W0T_0, W0T_1);

    // ---- S1: {sdti@XTF, g1_0@W0T_0, g1_1@W0T_1}
    gemm_bt_batch<<<dim3(1, 24, 3 * ZSPLIT), 256, 0, stream>>>(
        sdti, XTF, g1c[0], W0T_0, g1c[1], W0T_1, part);
    reduce_trans_b<<<dim3(96, 4, 3), 256, 0, stream>>>(part,
        XT2, ZT_0, ZT_1, nullptr, Zrm_0, Zrm_1, nullptr, nullptr);

    // ---- S2: {sdti@XT2, b0_0@ZT_0, b0_1@ZT_1}; b0 -> DTI attention write
    gemm_bt_batch<<<dim3(1, 24, 3 * ZSPLIT), 256, 0, stream>>>(
        sdti, XT2, b0c[0], ZT_0, b0c[1], ZT_1, part);
    reduce_trans_b<<<dim3(96, 4, 3), 256, 0, stream>>>(part,
        nullptr, UT_0, UT_1, nullptr, nullptr, nullptr, ap, conv);

    // ---- S3: {a0_0@UT_0, a0_1@UT_1} ; hop1 combine
    gemm_bt_batch<<<dim3(1, 24, 2 * ZSPLIT), 256, 0, stream>>>(
        a0c[0], UT_0, a0c[1], UT_1, nullptr, nullptr, part);
    combine_mid2<<<dim3(96, 4, 2), 256, 0, stream>>>(part, Zrm_0, Zrm_1, fb,
        rsv2, dinv2, WpT_0, WpT_1, Wprm_0, Wprm_1);

    // ---- S4..S6: hop2
    gemm_bt_batch<<<dim3(1, 24, 2 * ZSPLIT), 256, 0, stream>>>(
        g1c[0], WpT_0, g1c[1], WpT_1, nullptr, nullptr, part);
    reduce_trans_b<<<dim3(96, 4, 2), 256, 0, stream>>>(part,
        ZT_0, ZT_1, nullptr, Zrm_0, Zrm_1, nullptr, nullptr, nullptr);
    gemm_bt_batch<<<dim3(1, 24, 2 * ZSPLIT), 256, 0, stream>>>(
        b0c[0], ZT_0, b0c[1], ZT_1, nullptr, nullptr, part);
    reduce_trans_b<<<dim3(96, 4, 2), 256, 0, stream>>>(part,
        UT_0, UT_1, nullptr, nullptr, nullptr, nullptr, nullptr, nullptr);
    gemm_bt_batch<<<dim3(1, 24, 2 * ZSPLIT), 256, 0, stream>>>(
        a0c[0], UT_0, a0c[1], UT_1, nullptr, nullptr, part);
    combine_att2<<<1500, 256, 0, stream>>>(part, Zrm_0, Zrm_1, Wprm_0, Wprm_1,
        rsv2, dinv2, ap, conv);

    // ---- final: sigmoid(drug @ prot^T)
    cast_split<<<1536, 256, 0, stream>>>(conv, dF, pF);
    gemm_sig<<<dim3(16, 8), 256, 0, stream>>>(dF, pF, out, 128, 128, 128, 2000, 1000, 2000);
}

// Round 9
// 269.781 us; speedup vs baseline: 1.1051x; 1.1051x over previous
//
#include <hip/hip_runtime.h>
#include <hip/hip_bf16.h>

typedef __attribute__((ext_vector_type(8))) __bf16 bf16x8;
typedef __attribute__((ext_vector_type(4))) float floatx4;

#define NVALID 3000
#define NPAD   3072
#define FEA    128
#define ZSPLIT 8
#define KCHUNK 384
#define PSTRIDE 393216   // NPAD*128 (elements)
#define SLOT   ((size_t)ZSPLIT * PSTRIDE)

// async global->LDS, 16B per lane
__device__ __forceinline__ void gload16(const void* g, void* l) {
    __builtin_amdgcn_global_load_lds(
        (const __attribute__((address_space(1))) void*)g,
        (__attribute__((address_space(3))) void*)l,
        16, 0, 0);
}

__device__ __forceinline__ float b2f(__hip_bfloat16 h) { return __bfloat162float(h); }

// ---------------------------------------------------------------- fused 3-layer MLP (row-independent)
__global__ __launch_bounds__(256) void mlp_fused(
    const float* __restrict__ Xd, const float* __restrict__ Xp,
    const float* __restrict__ Wd1, const float* __restrict__ bd1,
    const float* __restrict__ Wd2, const float* __restrict__ bd2,
    const float* __restrict__ Wd3, const float* __restrict__ bd3,
    const float* __restrict__ Wp1, const float* __restrict__ bp1,
    const float* __restrict__ Wp2, const float* __restrict__ bp2,
    const float* __restrict__ Wp3, const float* __restrict__ bp3,
    float* __restrict__ Y)
{
    const bool isP = blockIdx.x >= 125;
    const float* X  = isP ? Xp : Xd;
    const float* W1 = isP ? Wp1 : Wd1; const float* b1 = isP ? bp1 : bd1;
    const float* W2 = isP ? Wp2 : Wd2; const float* b2 = isP ? bp2 : bd2;
    const float* W3 = isP ? Wp3 : Wd3; const float* b3 = isP ? bp3 : bd3;
    const int m0loc = (isP ? (blockIdx.x - 125) : blockIdx.x) * 8;
    const int m0out = blockIdx.x * 8;

    __shared__ float S0[8][128], S1[8][128];
    const int t = threadIdx.x;
    for (int s2 = t; s2 < 1024; s2 += 256) {
        int r = s2 >> 7, ii = s2 & 127;
        S0[r][ii] = X[(size_t)(m0loc + r) * 128 + ii];
    }
    __syncthreads();
    const int o = t & 127, rh = t >> 7;

    {
        float a0 = 0.f, a1 = 0.f, a2 = 0.f, a3 = 0.f;
        const float* wr = W1 + (size_t)o * 128;
        for (int i = 0; i < 128; ++i) {
            float w = wr[i];
            a0 += S0[rh + 0][i] * w; a1 += S0[rh + 2][i] * w;
            a2 += S0[rh + 4][i] * w; a3 += S0[rh + 6][i] * w;
        }
        float bo = b1[o];
        S1[rh + 0][o] = fmaxf(a0 + bo, 0.f);
        S1[rh + 2][o] = fmaxf(a1 + bo, 0.f);
        S1[rh + 4][o] = fmaxf(a2 + bo, 0.f);
        S1[rh + 6][o] = fmaxf(a3 + bo, 0.f);
    }
    __syncthreads();
    {
        float a0 = 0.f, a1 = 0.f, a2 = 0.f, a3 = 0.f;
        const float* wr = W2 + (size_t)o * 128;
        for (int i = 0; i < 128; ++i) {
            float w = wr[i];
            a0 += S1[rh + 0][i] * w; a1 += S1[rh + 2][i] * w;
            a2 += S1[rh + 4][i] * w; a3 += S1[rh + 6][i] * w;
        }
        float bo = b2[o];
        S0[rh + 0][o] = fmaxf(a0 + bo, 0.f);
        S0[rh + 2][o] = fmaxf(a1 + bo, 0.f);
        S0[rh + 4][o] = fmaxf(a2 + bo, 0.f);
        S0[rh + 6][o] = fmaxf(a3 + bo, 0.f);
    }
    __syncthreads();
    {
        float a0 = 0.f, a1 = 0.f, a2 = 0.f, a3 = 0.f;
        const float* wr = W3 + (size_t)o * 128;
        for (int i = 0; i < 128; ++i) {
            float w = wr[i];
            a0 += S0[rh + 0][i] * w; a1 += S0[rh + 2][i] * w;
            a2 += S0[rh + 4][i] * w; a3 += S0[rh + 6][i] * w;
        }
        float bo = b3[o];
        Y[(size_t)(m0out + rh + 0) * 128 + o] = fmaxf(a0 + bo, 0.f);
        Y[(size_t)(m0out + rh + 2) * 128 + o] = fmaxf(a1 + bo, 0.f);
        Y[(size_t)(m0out + rh + 4) * 128 + o] = fmaxf(a2 + bo, 0.f);
        Y[(size_t)(m0out + rh + 6) * 128 + o] = fmaxf(a3 + bo, 0.f);
    }
}

// ---------------------------------------------------------------- softmax5
__device__ __forceinline__ void softmax5(const float* __restrict__ w, float* s)
{
    float m = w[0];
    #pragma unroll
    for (int e = 1; e < 5; ++e) m = fmaxf(m, w[e]);
    float sum = 0.f;
    #pragma unroll
    for (int e = 0; e < 5; ++e) { s[e] = __expf(w[e] - m); sum += s[e]; }
    float r = 1.f / sum;
    #pragma unroll
    for (int e = 0; e < 5; ++e) s[e] *= r;
}

// ---------------------------------------------------------------- gtconv: one full row per block (384 thr x 8 cols)
// fused: row sums of b00,g10,b01,g11 -> r1v[4][NPAD]
__global__ __launch_bounds__(384) void gtconv_fused(
    const float* __restrict__ A, const float* __restrict__ w0a,
    const float* __restrict__ w0b, const float* __restrict__ w1,
    __hip_bfloat16* __restrict__ a00, __hip_bfloat16* __restrict__ b00,
    __hip_bfloat16* __restrict__ g10,
    __hip_bfloat16* __restrict__ a01, __hip_bfloat16* __restrict__ b01,
    __hip_bfloat16* __restrict__ g11,
    float* __restrict__ r1v)
{
    float sw[6][5];
    softmax5(w0a + 0, sw[0]); softmax5(w0b + 0, sw[1]); softmax5(w1 + 0, sw[2]);
    softmax5(w0a + 5, sw[3]); softmax5(w0b + 5, sw[4]); softmax5(w1 + 5, sw[5]);

    const int i  = blockIdx.x;
    const int t  = threadIdx.x;
    const int j0 = t * 8;                 // 3000 = 375*8: threads >=375 are all-pad
    float acc[6][8] = {};
    if (i < NVALID && j0 < NVALID) {
        #pragma unroll
        for (int e = 0; e < 5; ++e) {
            const float* Ae = A + (size_t)e * 9000000 + (size_t)i * 3000 + j0;
            float4 v0 = *reinterpret_cast<const float4*>(Ae);
            float4 v1 = *reinterpret_cast<const float4*>(Ae + 4);
            float x[8] = { v0.x, v0.y, v0.z, v0.w, v1.x, v1.y, v1.z, v1.w };
            #pragma unroll
            for (int m = 0; m < 6; ++m) {
                float se = sw[m][e];
                #pragma unroll
                for (int u = 0; u < 8; ++u) acc[m][u] += se * x[u];
            }
        }
    }
    __hip_bfloat16* dsts[6] = { a00, b00, g10, a01, b01, g11 };
    const size_t base = (size_t)i * NPAD + j0;
    float rs[4];  // rounded row-sums of b00,g10,b01,g11
    #pragma unroll
    for (int m = 0; m < 6; ++m) {
        __align__(16) __hip_bfloat16 h[8];
        float s = 0.f;
        #pragma unroll
        for (int u = 0; u < 8; ++u) {
            h[u] = __float2bfloat16(acc[m][u]);
            s += b2f(h[u]);
        }
        *reinterpret_cast<uint4*>(&dsts[m][base]) = *reinterpret_cast<const uint4*>(h);
        if (m == 1) rs[0] = s; else if (m == 2) rs[1] = s;
        else if (m == 4) rs[2] = s; else if (m == 5) rs[3] = s;
    }
    __shared__ float red[6][4];
    #pragma unroll
    for (int q = 0; q < 4; ++q) {
        float s = rs[q];
        #pragma unroll
        for (int off = 32; off > 0; off >>= 1) s += __shfl_down(s, off);
        if ((t & 63) == 0) red[t >> 6][q] = s;
    }
    __syncthreads();
    if (t == 0) {
        #pragma unroll
        for (int q = 0; q < 4; ++q) {
            float s = red[0][q] + red[1][q] + red[2][q]
                    + red[3][q] + red[4][q] + red[5][q];
            r1v[(size_t)q * NPAD + i] = s;
        }
    }
}

// ---------------------------------------------------------------- batched degree matvecs
__global__ __launch_bounds__(256) void matvec_degA(
    const __hip_bfloat16* __restrict__ a0_0, const __hip_bfloat16* __restrict__ a0_1,
    const __hip_bfloat16* __restrict__ b0_0, const __hip_bfloat16* __restrict__ b0_1,
    const float* __restrict__ r1v,
    float* __restrict__ dinv2, float* __restrict__ mv12)
{
    const int y = blockIdx.y;
    const __hip_bfloat16* M = (y == 0) ? a0_0 : (y == 1) ? a0_1 : (y == 2) ? b0_0 : b0_1;
    const float* v = (y == 0) ? r1v : (y == 1) ? r1v + 2 * NPAD
                   : (y == 2) ? r1v + NPAD : r1v + 3 * NPAD;
    const size_t i = blockIdx.x;
    const int t = threadIdx.x;
    const __hip_bfloat16* row = M + i * NPAD;
    float s = 0.f;
    for (int k = t * 8; k < NPAD; k += 2048) {
        uint4 u = *reinterpret_cast<const uint4*>(&row[k]);
        const unsigned short* us = reinterpret_cast<const unsigned short*>(&u);
        #pragma unroll
        for (int e = 0; e < 8; ++e)
            s += __uint_as_float(((unsigned int)us[e]) << 16) * v[k + e];
    }
    #pragma unroll
    for (int off = 32; off > 0; off >>= 1) s += __shfl_down(s, off);
    __shared__ float red[4];
    if ((t & 63) == 0) red[t >> 6] = s;
    __syncthreads();
    if (t == 0) {
        float tot = red[0] + red[1] + red[2] + red[3];
        if (y < 2) dinv2[(size_t)y * NPAD + i] = 1.f / (tot + 1.f);
        else       mv12[(size_t)(y - 2) * NPAD + i] = tot;
    }
}

__global__ __launch_bounds__(256) void matvec_degB(
    const __hip_bfloat16* __restrict__ a0_0, const __hip_bfloat16* __restrict__ a0_1,
    const float* __restrict__ mv12, const float* __restrict__ dinv2,
    const float* __restrict__ r1v, float* __restrict__ rsv2)
{
    const int c = blockIdx.y;
    const __hip_bfloat16* M = c ? a0_1 : a0_0;
    const float* v = mv12 + (size_t)c * NPAD;
    const float* add = r1v + (size_t)(2 * c + 1) * NPAD;
    const size_t i = blockIdx.x;
    const int t = threadIdx.x;
    const __hip_bfloat16* row = M + i * NPAD;
    float s = 0.f;
    for (int k = t * 8; k < NPAD; k += 2048) {
        uint4 u = *reinterpret_cast<const uint4*>(&row[k]);
        const unsigned short* us = reinterpret_cast<const unsigned short*>(&u);
        #pragma unroll
        for (int e = 0; e < 8; ++e)
            s += __uint_as_float(((unsigned int)us[e]) << 16) * v[k + e];
    }
    #pragma unroll
    for (int off = 32; off > 0; off >>= 1) s += __shfl_down(s, off);
    __shared__ float red[4];
    if ((t & 63) == 0) red[t >> 6] = s;
    __syncthreads();
    if (t == 0) {
        float tot = red[0] + red[1] + red[2] + red[3];
        rsv2[(size_t)c * NPAD + i] =
            rsqrtf(dinv2[(size_t)c * NPAD + i] * (tot + add[i]) + 2.f);
    }
}

// ---------------------------------------------------------------- DTI degree + scale (f32)
__global__ __launch_bounds__(256) void rowdeg_f32(
    const float* __restrict__ src, float* __restrict__ outv)
{
    const int i = blockIdx.x, t = threadIdx.x;
    float s = 0.f;
    if (i < NVALID) {
        const float* row = src + (size_t)i * 3000;
        for (int j4 = t; j4 < 750; j4 += 256) {
            float4 v = *reinterpret_cast<const float4*>(row + j4 * 4);
            s += v.x + v.y + v.z + v.w;
        }
    }
    #pragma unroll
    for (int off = 32; off > 0; off >>= 1) s += __shfl_down(s, off);
    __shared__ float red[4];
    if ((t & 63) == 0) red[t >> 6] = s;
    __syncthreads();
    if (t == 0) {
        float tot = red[0] + red[1] + red[2] + red[3];
        outv[i] = rsqrtf(tot + 2.f);
    }
}

__global__ __launch_bounds__(256) void scale_cast_f32(
    const float* __restrict__ src, int lds_, int nvalid,
    const float* __restrict__ vec, __hip_bfloat16* __restrict__ dst)
{
    const int i = blockIdx.y;
    const int j0 = (blockIdx.x * 256 + threadIdx.x) * 4;
    const float vi = vec[i];
    float v[4];
    if (i < nvalid && j0 + 3 < nvalid) {
        float4 f = *reinterpret_cast<const float4*>(src + (size_t)i * lds_ + j0);
        v[0] = f.x; v[1] = f.y; v[2] = f.z; v[3] = f.w;
    } else {
        #pragma unroll
        for (int u = 0; u < 4; ++u) {
            int j = j0 + u;
            v[u] = (i < nvalid && j < nvalid) ? src[(size_t)i * lds_ + j] : 0.f;
        }
    }
    #pragma unroll
    for (int u = 0; u < 4; ++u) {
        int j = j0 + u;
        if (j == i && i < nvalid) v[u] += 2.f;
        v[u] *= vi * vec[j];
    }
    __align__(8) __hip_bfloat16 h[4];
    #pragma unroll
    for (int u = 0; u < 4; ++u) h[u] = __float2bfloat16(v[u]);
    *reinterpret_cast<uint2*>(&dst[(size_t)i * NPAD + j0]) =
        *reinterpret_cast<const uint2*>(h);
}

// ---------------------------------------------------------------- transpose feature (f32 -> bf16^T)
__global__ __launch_bounds__(256) void transpose_feat(
    const float* __restrict__ X, int nvalid, __hip_bfloat16* __restrict__ XT)
{
    __shared__ float Ts[32][33];
    const int k0 = blockIdx.x * 32, n0 = blockIdx.y * 32;
    const int t = threadIdx.x, tr = t >> 5, tc = t & 31;
    #pragma unroll
    for (int p = 0; p < 4; ++p) {
        int k = k0 + tr + p * 8;
        Ts[tr + p * 8][tc] = (k < nvalid) ? X[(size_t)k * 128 + n0 + tc] : 0.f;
    }
    __syncthreads();
    #pragma unroll
    for (int p = 0; p < 4; ++p) {
        int n = tr + p * 8;
        XT[(size_t)(n0 + n) * NPAD + k0 + tc] = __float2bfloat16(Ts[tc][n]);
    }
}

// ---------------------------------------------------------------- scale columns of XT by rsv_c -> W0T_c
__global__ __launch_bounds__(256) void scale_colsT2(
    const __hip_bfloat16* __restrict__ XT, const float* __restrict__ rsv2,
    __hip_bfloat16* __restrict__ W0T_0, __hip_bfloat16* __restrict__ W0T_1)
{
    const int c = blockIdx.z;
    const float* s = rsv2 + (size_t)c * NPAD;
    __hip_bfloat16* W0T = c ? W0T_1 : W0T_0;
    const int f = blockIdx.y;
    const int k0 = (blockIdx.x * 256 + threadIdx.x) * 8;
    if (k0 >= NPAD) return;
    uint4 u = *reinterpret_cast<const uint4*>(&XT[(size_t)f * NPAD + k0]);
    const unsigned short* us = reinterpret_cast<const unsigned short*>(&u);
    __align__(16) __hip_bfloat16 h[8];
    #pragma unroll
    for (int e = 0; e < 8; ++e) {
        float x = __uint_as_float(((unsigned int)us[e]) << 16);
        h[e] = __float2bfloat16(x * s[k0 + e]);
    }
    *reinterpret_cast<uint4*>(&W0T[(size_t)f * NPAD + k0]) =
        *reinterpret_cast<const uint4*>(h);
}

// ---------------------------------------------------------------- batched thin GEMM (up to 3 A/B pairs)
// grid (1, 24, NB*ZSPLIT); writes bf16 partials at slot b.
__global__ __launch_bounds__(256, 3) void gemm_bt_batch(
    const __hip_bfloat16* __restrict__ A0, const __hip_bfloat16* __restrict__ B0,
    const __hip_bfloat16* __restrict__ A1, const __hip_bfloat16* __restrict__ B1,
    const __hip_bfloat16* __restrict__ A2, const __hip_bfloat16* __restrict__ B2,
    __hip_bfloat16* __restrict__ part)
{
    const int b  = blockIdx.z / ZSPLIT;
    const int zz = blockIdx.z % ZSPLIT;
    const __hip_bfloat16* A  = (b == 0) ? A0 : (b == 1) ? A1 : A2;
    const __hip_bfloat16* BT = (b == 0) ? B0 : (b == 1) ? B1 : B2;
    __hip_bfloat16* C = part + (size_t)b * SLOT + (size_t)zz * PSTRIDE;

    __shared__ __align__(16) __hip_bfloat16 As[128 * 32];
    __shared__ __align__(16) __hip_bfloat16 Bs[128 * 32];
    const int t = threadIdx.x;
    const int lane = t & 63;
    const int w = t >> 6;
    const int wm = w >> 1, wn = w & 1;
    const int tm = blockIdx.y;
    const int kbeg = zz * KCHUNK;

    const int srow = lane >> 2;
    const int skg  = (lane & 3) * 8;
    const __hip_bfloat16* Ag = A  + (size_t)(tm * 128 + w * 32 + srow) * NPAD + skg;
    const __hip_bfloat16* Bg = BT + (size_t)(w * 32 + srow) * NPAD + skg;
    __hip_bfloat16* Al0 = &As[w * 1024];
    __hip_bfloat16* Al1 = &As[w * 1024 + 512];
    __hip_bfloat16* Bl0 = &Bs[w * 1024];
    __hip_bfloat16* Bl1 = &Bs[w * 1024 + 512];

    floatx4 acc[4][4] = {};

    for (int k0 = kbeg; k0 < kbeg + KCHUNK; k0 += 32) {
        __syncthreads();
        gload16(Ag + k0,             Al0);
        gload16(Ag + 16 * NPAD + k0, Al1);
        gload16(Bg + k0,             Bl0);
        gload16(Bg + 16 * NPAD + k0, Bl1);
        __syncthreads();

        bf16x8 af[4], bfv[4];
        const int koff = (lane >> 4) * 8;
        #pragma unroll
        for (int mi = 0; mi < 4; ++mi)
            af[mi] = *reinterpret_cast<const bf16x8*>(
                &As[(wm * 64 + mi * 16 + (lane & 15)) * 32 + koff]);
        #pragma unroll
        for (int ni = 0; ni < 4; ++ni)
            bfv[ni] = *reinterpret_cast<const bf16x8*>(
                &Bs[(wn * 64 + ni * 16 + (lane & 15)) * 32 + koff]);
        #pragma unroll
        for (int mi = 0; mi < 4; ++mi)
            #pragma unroll
            for (int ni = 0; ni < 4; ++ni)
                acc[mi][ni] = __builtin_amdgcn_mfma_f32_16x16x32_bf16(
                    af[mi], bfv[ni], acc[mi][ni], 0, 0, 0);
    }

    const int r0 = tm * 128 + wm * 64 + ((lane >> 4) << 2);
    const int c0 = wn * 64 + (lane & 15);
    #pragma unroll
    for (int mi = 0; mi < 4; ++mi)
        #pragma unroll
        for (int ni = 0; ni < 4; ++ni)
            #pragma unroll
            for (int r = 0; r < 4; ++r)
                C[(size_t)(r0 + mi * 16 + r) * 128 + c0 + ni * 16] =
                    __float2bfloat16(acc[mi][ni][r]);
}

// ---------------------------------------------------------------- final GEMM (sigmoid epilogue)
__global__ __launch_bounds__(256, 3) void gemm_sig(
    const __hip_bfloat16* __restrict__ A, const __hip_bfloat16* __restrict__ BT,
    float* __restrict__ C, int Kchunk, int lda, int ldb, int ldc,
    int Mvalid, int Nvalid)
{
    __shared__ __align__(16) __hip_bfloat16 As[128 * 32];
    __shared__ __align__(16) __hip_bfloat16 Bs[128 * 32];
    const int t = threadIdx.x;
    const int lane = t & 63;
    const int w = t >> 6;
    const int wm = w >> 1, wn = w & 1;
    const int tm = blockIdx.y, tn = blockIdx.x;

    const int srow = lane >> 2;
    const int skg  = (lane & 3) * 8;
    const __hip_bfloat16* Ag = A  + (size_t)(tm * 128 + w * 32 + srow) * lda + skg;
    const __hip_bfloat16* Bg = BT + (size_t)(tn * 128 + w * 32 + srow) * ldb + skg;
    __hip_bfloat16* Al0 = &As[w * 1024];
    __hip_bfloat16* Al1 = &As[w * 1024 + 512];
    __hip_bfloat16* Bl0 = &Bs[w * 1024];
    __hip_bfloat16* Bl1 = &Bs[w * 1024 + 512];

    floatx4 acc[4][4] = {};

    for (int k0 = 0; k0 < Kchunk; k0 += 32) {
        __syncthreads();
        gload16(Ag + k0,            Al0);
        gload16(Ag + 16 * lda + k0, Al1);
        gload16(Bg + k0,            Bl0);
        gload16(Bg + 16 * ldb + k0, Bl1);
        __syncthreads();

        bf16x8 af[4], bfv[4];
        const int koff = (lane >> 4) * 8;
        #pragma unroll
        for (int mi = 0; mi < 4; ++mi)
            af[mi] = *reinterpret_cast<const bf16x8*>(
                &As[(wm * 64 + mi * 16 + (lane & 15)) * 32 + koff]);
        #pragma unroll
        for (int ni = 0; ni < 4; ++ni)
            bfv[ni] = *reinterpret_cast<const bf16x8*>(
                &Bs[(wn * 64 + ni * 16 + (lane & 15)) * 32 + koff]);
        #pragma unroll
        for (int mi = 0; mi < 4; ++mi)
            #pragma unroll
            for (int ni = 0; ni < 4; ++ni)
                acc[mi][ni] = __builtin_amdgcn_mfma_f32_16x16x32_bf16(
                    af[mi], bfv[ni], acc[mi][ni], 0, 0, 0);
    }

    const int r0 = tm * 128 + wm * 64 + ((lane >> 4) << 2);
    const int c0 = tn * 128 + wn * 64 + (lane & 15);
    #pragma unroll
    for (int mi = 0; mi < 4; ++mi)
        #pragma unroll
        for (int ni = 0; ni < 4; ++ni) {
            const int col = c0 + ni * 16;
            #pragma unroll
            for (int r = 0; r < 4; ++r) {
                const int row = r0 + mi * 16 + r;
                if (row < Mvalid && col < Nvalid)
                    C[(size_t)row * ldc + col] =
                        1.f / (1.f + __expf(-acc[mi][ni][r]));
            }
        }
}

// ---------------------------------------------------------------- batched K-split reduce + transpose (bf16 partials)
// grid (96, 4, NB). For b==0 with conv!=nullptr: DTI attention write (no transpose).
__global__ __launch_bounds__(256) void reduce_trans_b(
    const __hip_bfloat16* __restrict__ part,
    __hip_bfloat16* __restrict__ X0, __hip_bfloat16* __restrict__ X1,
    __hip_bfloat16* __restrict__ X2,
    __hip_bfloat16* __restrict__ R0, __hip_bfloat16* __restrict__ R1,
    __hip_bfloat16* __restrict__ R2,
    const float* __restrict__ ap, float* __restrict__ conv)
{
    const int b = blockIdx.z;
    const __hip_bfloat16* Pp = part + (size_t)b * SLOT;
    const int k0 = blockIdx.x * 32, n0 = blockIdx.y * 32;
    const int t = threadIdx.x, tr = t >> 5, tc = t & 31;

    if (b == 0 && conv != nullptr) {
        float a0 = ap[0], a1 = ap[1], a2 = ap[2];
        float m = fmaxf(a0, fmaxf(a1, a2));
        float e0 = __expf(a0 - m), e1 = __expf(a1 - m), e2 = __expf(a2 - m);
        float att0 = e0 / (e0 + e1 + e2);
        #pragma unroll
        for (int p = 0; p < 4; ++p) {
            int i = k0 + tr + p * 8;
            float s = 0.f;
            #pragma unroll
            for (int z = 0; z < ZSPLIT; ++z)
                s += b2f(Pp[(size_t)z * PSTRIDE + (size_t)i * 128 + n0 + tc]);
            conv[(size_t)i * 128 + n0 + tc] = att0 * s;
        }
        return;
    }

    __hip_bfloat16* XT = (b == 0) ? X0 : (b == 1) ? X1 : X2;
    __hip_bfloat16* Rm = (b == 0) ? R0 : (b == 1) ? R1 : R2;
    __shared__ float Ts[32][33];
    #pragma unroll
    for (int p = 0; p < 4; ++p) {
        int i = k0 + tr + p * 8;
        float s = 0.f;
        #pragma unroll
        for (int z = 0; z < ZSPLIT; ++z)
            s += b2f(Pp[(size_t)z * PSTRIDE + (size_t)i * 128 + n0 + tc]);
        Ts[tr + p * 8][tc] = s;
        if (Rm) Rm[(size_t)i * 128 + n0 + tc] = __float2bfloat16(s);
    }
    __syncthreads();
    #pragma unroll
    for (int p = 0; p < 4; ++p) {
        int n = tr + p * 8;
        XT[(size_t)(n0 + n) * NPAD + k0 + tc] = __float2bfloat16(Ts[tc][n]);
    }
}

// ---------------------------------------------------------------- batched hop1 combine (grid (96,4,2))
__global__ __launch_bounds__(256) void combine_mid2(
    const __hip_bfloat16* __restrict__ part,
    const __hip_bfloat16* __restrict__ Zrm0, const __hip_bfloat16* __restrict__ Zrm1,
    const float* __restrict__ X,
    const float* __restrict__ rsv2, const float* __restrict__ dinv2,
    __hip_bfloat16* __restrict__ WpT0, __hip_bfloat16* __restrict__ WpT1,
    __hip_bfloat16* __restrict__ Wprm0, __hip_bfloat16* __restrict__ Wprm1)
{
    const int c = blockIdx.z;
    const __hip_bfloat16* Vp = part + (size_t)c * SLOT;
    const __hip_bfloat16* Zrm = c ? Zrm1 : Zrm0;
    const float* sv = rsv2 + (size_t)c * NPAD;
    const float* dv = dinv2 + (size_t)c * NPAD;
    __hip_bfloat16* WpT  = c ? WpT1 : WpT0;
    __hip_bfloat16* Wprm = c ? Wprm1 : Wprm0;

    __shared__ float Ts[32][33];
    const int k0 = blockIdx.x * 32, n0 = blockIdx.y * 32;
    const int t = threadIdx.x, tr = t >> 5, tc = t & 31;
    #pragma unroll
    for (int p = 0; p < 4; ++p) {
        int i = k0 + tr + p * 8;
        int f = n0 + tc;
        float vsum = b2f(Zrm[(size_t)i * 128 + f]);
        #pragma unroll
        for (int z = 0; z < ZSPLIT; ++z)
            vsum += b2f(Vp[(size_t)z * PSTRIDE + (size_t)i * 128 + f]);
        float x  = (i < NVALID) ? X[(size_t)i * 128 + f] : 0.f;
        float si = sv[i];
        float out1 = si * dv[i] * vsum + 2.f * si * si * x;
        float wv = si * out1;
        Ts[tr + p * 8][tc] = wv;
        Wprm[(size_t)i * 128 + f] = __float2bfloat16(wv);
    }
    __syncthreads();
    #pragma unroll
    for (int p = 0; p < 4; ++p) {
        int n = tr + p * 8;
        WpT[(size_t)(n0 + n) * NPAD + k0 + tc] = __float2bfloat16(Ts[tc][n]);
    }
}

// ---------------------------------------------------------------- hop2 combine + attention for BOTH channels
__global__ __launch_bounds__(256) void combine_att2(
    const __hip_bfloat16* __restrict__ part,
    const __hip_bfloat16* __restrict__ Zrm0, const __hip_bfloat16* __restrict__ Zrm1,
    const __hip_bfloat16* __restrict__ Wprm0, const __hip_bfloat16* __restrict__ Wprm1,
    const float* __restrict__ rsv2, const float* __restrict__ dinv2,
    const float* __restrict__ ap, float* __restrict__ conv)
{
    const int idx = blockIdx.x * 256 + threadIdx.x;  // grid 1500 -> 3000*128
    const int i = idx >> 7;
    float v0 = b2f(Zrm0[idx]);
    float v1 = b2f(Zrm1[idx]);
    #pragma unroll
    for (int z = 0; z < ZSPLIT; ++z) {
        v0 += b2f(part[(size_t)z * PSTRIDE + idx]);
        v1 += b2f(part[SLOT + (size_t)z * PSTRIDE + idx]);
    }
    float s0 = rsv2[i],        d0 = dinv2[i];
    float s1 = rsv2[NPAD + i], d1 = dinv2[NPAD + i];
    float o0 = s0 * d0 * v0 + 2.f * s0 * b2f(Wprm0[idx]);
    float o1 = s1 * d1 * v1 + 2.f * s1 * b2f(Wprm1[idx]);
    float a0 = ap[0], a1 = ap[1], a2 = ap[2];
    float m = fmaxf(a0, fmaxf(a1, a2));
    float e0 = __expf(a0 - m), e1 = __expf(a1 - m), e2 = __expf(a2 - m);
    float inv = 1.f / (e0 + e1 + e2);
    conv[idx] += (e1 * inv) * o0 + (e2 * inv) * o1;
}

// ---------------------------------------------------------------- final split+cast
__global__ __launch_bounds__(256) void cast_split(
    const float* __restrict__ acc, __hip_bfloat16* __restrict__ dF,
    __hip_bfloat16* __restrict__ pF)
{
    const int idx = blockIdx.x * 256 + threadIdx.x;
    if (idx < 1024 * 128) {
        int r = idx >> 7;
        dF[idx] = __float2bfloat16(r < 1000 ? acc[idx] : 0.f);
    } else {
        int j = idx - 1024 * 128;
        int r = j >> 7;
        pF[j] = __float2bfloat16(r < 2000 ? acc[(size_t)(1000 + r) * 128 + (j & 127)] : 0.f);
    }
}

// ================================================================ launch
extern "C" void kernel_launch(void* const* d_in, const int* in_sizes, int n_in,
                              void* d_out, int out_size, void* d_ws, size_t ws_size,
                              hipStream_t stream)
{
    const float* A     = (const float*)d_in[0];
    const float* DTI   = (const float*)d_in[1];
    const float* drugS = (const float*)d_in[2];
    const float* protS = (const float*)d_in[3];
    const float* w0a   = (const float*)d_in[4];
    const float* w0b   = (const float*)d_in[5];
    const float* w1g   = (const float*)d_in[6];
    const float* ap    = (const float*)d_in[7];
    const float* wd1 = (const float*)d_in[10]; const float* bd1 = (const float*)d_in[11];
    const float* wd2 = (const float*)d_in[12]; const float* bd2 = (const float*)d_in[13];
    const float* wd3 = (const float*)d_in[14]; const float* bd3 = (const float*)d_in[15];
    const float* wp1 = (const float*)d_in[16]; const float* bp1 = (const float*)d_in[17];
    const float* wp2 = (const float*)d_in[18]; const float* bp2 = (const float*)d_in[19];
    const float* wp3 = (const float*)d_in[20]; const float* bp3 = (const float*)d_in[21];
    float* out = (float*)d_out;

    const size_t SQ_BF  = (size_t)NPAD * NPAD * 2;
    const size_t PAN_BF = (size_t)128 * NPAD * 2;
    char* p = (char*)d_ws;
    auto alloc = [&](size_t sz) { char* r = p; p += (sz + 255) & ~(size_t)255; return r; };
    __hip_bfloat16* sdti = (__hip_bfloat16*)alloc(SQ_BF);
    __hip_bfloat16* a0c[2], *b0c[2], *g1c[2];
    for (int c = 0; c < 2; ++c) {
        a0c[c] = (__hip_bfloat16*)alloc(SQ_BF);
        b0c[c] = (__hip_bfloat16*)alloc(SQ_BF);
        g1c[c] = (__hip_bfloat16*)alloc(SQ_BF);
    }
    __hip_bfloat16* part = (__hip_bfloat16*)alloc((size_t)3 * SLOT * 2);
    float* r1v   = (float*)alloc((size_t)4 * NPAD * 4);
    float* dinv2 = (float*)alloc((size_t)2 * NPAD * 4);
    float* mv12  = (float*)alloc((size_t)2 * NPAD * 4);
    float* rsv2  = (float*)alloc((size_t)2 * NPAD * 4);
    float* degv  = (float*)alloc((size_t)NPAD * 4);
    float* fb    = (float*)alloc((size_t)NPAD * 128 * 4);
    float* conv  = (float*)alloc((size_t)NPAD * 128 * 4);
    __hip_bfloat16* XTF  = (__hip_bfloat16*)alloc(PAN_BF);
    __hip_bfloat16* XT2  = (__hip_bfloat16*)alloc(PAN_BF);
    __hip_bfloat16* W0T_0 = (__hip_bfloat16*)alloc(PAN_BF);
    __hip_bfloat16* W0T_1 = (__hip_bfloat16*)alloc(PAN_BF);
    __hip_bfloat16* ZT_0  = (__hip_bfloat16*)alloc(PAN_BF);
    __hip_bfloat16* ZT_1  = (__hip_bfloat16*)alloc(PAN_BF);
    __hip_bfloat16* Zrm_0 = (__hip_bfloat16*)alloc(PAN_BF);
    __hip_bfloat16* Zrm_1 = (__hip_bfloat16*)alloc(PAN_BF);
    __hip_bfloat16* UT_0  = (__hip_bfloat16*)alloc(PAN_BF);
    __hip_bfloat16* UT_1  = (__hip_bfloat16*)alloc(PAN_BF);
    __hip_bfloat16* WpT_0 = (__hip_bfloat16*)alloc(PAN_BF);
    __hip_bfloat16* WpT_1 = (__hip_bfloat16*)alloc(PAN_BF);
    __hip_bfloat16* Wprm_0 = (__hip_bfloat16*)alloc(PAN_BF);
    __hip_bfloat16* Wprm_1 = (__hip_bfloat16*)alloc(PAN_BF);
    __hip_bfloat16* dF = (__hip_bfloat16*)alloc((size_t)1024 * 128 * 2);
    __hip_bfloat16* pF = (__hip_bfloat16*)alloc((size_t)2048 * 128 * 2);
    if ((size_t)(p - (char*)d_ws) > ws_size) return;  // fail loud if ws too small

    // ---- fused MLPs -> fb; transpose
    mlp_fused<<<375, 256, 0, stream>>>(drugS, protS,
        wd1, bd1, wd2, bd2, wd3, bd3, wp1, bp1, wp2, bp2, wp3, bp3, fb);
    transpose_feat<<<dim3(96, 4), 256, 0, stream>>>(fb, 3000, XTF);

    // ---- gtconv (full-row blocks, fused rowsums)
    gtconv_fused<<<NPAD, 384, 0, stream>>>(A, w0a, w0b, w1g,
        a0c[0], b0c[0], g1c[0], a0c[1], b0c[1], g1c[1], r1v);

    // ---- DTI normalize
    rowdeg_f32<<<NPAD, 256, 0, stream>>>(DTI, degv);
    scale_cast_f32<<<dim3(3, NPAD), 256, 0, stream>>>(DTI, 3000, 3000, degv, sdti);

    // ---- batched degree matvecs + W0T
    matvec_degA<<<dim3(NPAD, 4), 256, 0, stream>>>(a0c[0], a0c[1], b0c[0], b0c[1],
        r1v, dinv2, mv12);
    matvec_degB<<<dim3(NPAD, 2), 256, 0, stream>>>(a0c[0], a0c[1], mv12, dinv2, r1v, rsv2);
    scale_colsT2<<<dim3(2, 128, 2), 256, 0, stream>>>(XTF, rsv2, W0T_0, W0T_1);

    // ---- S1: {sdti@XTF, g1_0@W0T_0, g1_1@W0T_1}
    gemm_bt_batch<<<dim3(1, 24, 3 * ZSPLIT), 256, 0, stream>>>(
        sdti, XTF, g1c[0], W0T_0, g1c[1], W0T_1, part);
    reduce_trans_b<<<dim3(96, 4, 3), 256, 0, stream>>>(part,
        XT2, ZT_0, ZT_1, nullptr, Zrm_0, Zrm_1, nullptr, nullptr);

    // ---- S2: {sdti@XT2, b0_0@ZT_0, b0_1@ZT_1}; b0 -> DTI attention write
    gemm_bt_batch<<<dim3(1, 24, 3 * ZSPLIT), 256, 0, stream>>>(
        sdti, XT2, b0c[0], ZT_0, b0c[1], ZT_1, part);
    reduce_trans_b<<<dim3(96, 4, 3), 256, 0, stream>>>(part,
        nullptr, UT_0, UT_1, nullptr, nullptr, nullptr, ap, conv);

    // ---- S3: {a0_0@UT_0, a0_1@UT_1} ; hop1 combine
    gemm_bt_batch<<<dim3(1, 24, 2 * ZSPLIT), 256, 0, stream>>>(
        a0c[0], UT_0, a0c[1], UT_1, nullptr, nullptr, part);
    combine_mid2<<<dim3(96, 4, 2), 256, 0, stream>>>(part, Zrm_0, Zrm_1, fb,
        rsv2, dinv2, WpT_0, WpT_1, Wprm_0, Wprm_1);

    // ---- S4..S6: hop2
    gemm_bt_batch<<<dim3(1, 24, 2 * ZSPLIT), 256, 0, stream>>>(
        g1c[0], WpT_0, g1c[1], WpT_1, nullptr, nullptr, part);
    reduce_trans_b<<<dim3(96, 4, 2), 256, 0, stream>>>(part,
        ZT_0, ZT_1, nullptr, Zrm_0, Zrm_1, nullptr, nullptr, nullptr);
    gemm_bt_batch<<<dim3(1, 24, 2 * ZSPLIT), 256, 0, stream>>>(
        b0c[0], ZT_0, b0c[1], ZT_1, nullptr, nullptr, part);
    reduce_trans_b<<<dim3(96, 4, 2), 256, 0, stream>>>(part,
        UT_0, UT_1, nullptr, nullptr, nullptr, nullptr, nullptr, nullptr);
    gemm_bt_batch<<<dim3(1, 24, 2 * ZSPLIT), 256, 0, stream>>>(
        a0c[0], UT_0, a0c[1], UT_1, nullptr, nullptr, part);
    combine_att2<<<1500, 256, 0, stream>>>(part, Zrm_0, Zrm_1, Wprm_0, Wprm_1,
        rsv2, dinv2, ap, conv);

    // ---- final: sigmoid(drug @ prot^T)
    cast_split<<<1536, 256, 0, stream>>>(conv, dF, pF);
    gemm_sig<<<dim3(16, 8), 256, 0, stream>>>(dF, pF, out, 128, 128, 128, 2000, 1000, 2000);
}

// Round 11
// 267.351 us; speedup vs baseline: 1.1152x; 1.0091x over previous
//
#include <hip/hip_runtime.h>
#include <hip/hip_bf16.h>

typedef __attribute__((ext_vector_type(8))) __bf16 bf16x8;
typedef __attribute__((ext_vector_type(4))) float floatx4;

#define NVALID 3000
#define NPAD   3072
#define FEA    128
#define ZSPLIT 8
#define KCHUNK 384
#define PSTRIDE 393216   // 128*NPAD (panel elements)
#define SLOT   ((size_t)ZSPLIT * PSTRIDE)

// async global->LDS, 16B per lane
__device__ __forceinline__ void gload16(const void* g, void* l) {
    __builtin_amdgcn_global_load_lds(
        (const __attribute__((address_space(1))) void*)g,
        (__attribute__((address_space(3))) void*)l,
        16, 0, 0);
}

__device__ __forceinline__ float b2f(__hip_bfloat16 h) { return __bfloat162float(h); }

// ---------------------------------------------------------------- fused 3-layer MLP
__global__ __launch_bounds__(256) void mlp_fused(
    const float* __restrict__ Xd, const float* __restrict__ Xp,
    const float* __restrict__ Wd1, const float* __restrict__ bd1,
    const float* __restrict__ Wd2, const float* __restrict__ bd2,
    const float* __restrict__ Wd3, const float* __restrict__ bd3,
    const float* __restrict__ Wp1, const float* __restrict__ bp1,
    const float* __restrict__ Wp2, const float* __restrict__ bp2,
    const float* __restrict__ Wp3, const float* __restrict__ bp3,
    float* __restrict__ Y)
{
    const bool isP = blockIdx.x >= 125;
    const float* X  = isP ? Xp : Xd;
    const float* W1 = isP ? Wp1 : Wd1; const float* b1 = isP ? bp1 : bd1;
    const float* W2 = isP ? Wp2 : Wd2; const float* b2 = isP ? bp2 : bd2;
    const float* W3 = isP ? Wp3 : Wd3; const float* b3 = isP ? bp3 : bd3;
    const int m0loc = (isP ? (blockIdx.x - 125) : blockIdx.x) * 8;
    const int m0out = blockIdx.x * 8;

    __shared__ float S0[8][128], S1[8][128];
    const int t = threadIdx.x;
    for (int s2 = t; s2 < 1024; s2 += 256) {
        int r = s2 >> 7, ii = s2 & 127;
        S0[r][ii] = X[(size_t)(m0loc + r) * 128 + ii];
    }
    __syncthreads();
    const int o = t & 127, rh = t >> 7;

    {
        float a0 = 0.f, a1 = 0.f, a2 = 0.f, a3 = 0.f;
        const float* wr = W1 + (size_t)o * 128;
        for (int i = 0; i < 128; ++i) {
            float w = wr[i];
            a0 += S0[rh + 0][i] * w; a1 += S0[rh + 2][i] * w;
            a2 += S0[rh + 4][i] * w; a3 += S0[rh + 6][i] * w;
        }
        float bo = b1[o];
        S1[rh + 0][o] = fmaxf(a0 + bo, 0.f);
        S1[rh + 2][o] = fmaxf(a1 + bo, 0.f);
        S1[rh + 4][o] = fmaxf(a2 + bo, 0.f);
        S1[rh + 6][o] = fmaxf(a3 + bo, 0.f);
    }
    __syncthreads();
    {
        float a0 = 0.f, a1 = 0.f, a2 = 0.f, a3 = 0.f;
        const float* wr = W2 + (size_t)o * 128;
        for (int i = 0; i < 128; ++i) {
            float w = wr[i];
            a0 += S1[rh + 0][i] * w; a1 += S1[rh + 2][i] * w;
            a2 += S1[rh + 4][i] * w; a3 += S1[rh + 6][i] * w;
        }
        float bo = b2[o];
        S0[rh + 0][o] = fmaxf(a0 + bo, 0.f);
        S0[rh + 2][o] = fmaxf(a1 + bo, 0.f);
        S0[rh + 4][o] = fmaxf(a2 + bo, 0.f);
        S0[rh + 6][o] = fmaxf(a3 + bo, 0.f);
    }
    __syncthreads();
    {
        float a0 = 0.f, a1 = 0.f, a2 = 0.f, a3 = 0.f;
        const float* wr = W3 + (size_t)o * 128;
        for (int i = 0; i < 128; ++i) {
            float w = wr[i];
            a0 += S0[rh + 0][i] * w; a1 += S0[rh + 2][i] * w;
            a2 += S0[rh + 4][i] * w; a3 += S0[rh + 6][i] * w;
        }
        float bo = b3[o];
        Y[(size_t)(m0out + rh + 0) * 128 + o] = fmaxf(a0 + bo, 0.f);
        Y[(size_t)(m0out + rh + 2) * 128 + o] = fmaxf(a1 + bo, 0.f);
        Y[(size_t)(m0out + rh + 4) * 128 + o] = fmaxf(a2 + bo, 0.f);
        Y[(size_t)(m0out + rh + 6) * 128 + o] = fmaxf(a3 + bo, 0.f);
    }
}

// ---------------------------------------------------------------- softmax5
__device__ __forceinline__ void softmax5(const float* __restrict__ w, float* s)
{
    float m = w[0];
    #pragma unroll
    for (int e = 1; e < 5; ++e) m = fmaxf(m, w[e]);
    float sum = 0.f;
    #pragma unroll
    for (int e = 0; e < 5; ++e) { s[e] = __expf(w[e] - m); sum += s[e]; }
    float r = 1.f / sum;
    #pragma unroll
    for (int e = 0; e < 5; ++e) s[e] *= r;
}

// ---------------------------------------------------------------- gtconv (full row per block, fused rowsums)
__global__ __launch_bounds__(384) void gtconv_fused(
    const float* __restrict__ A, const float* __restrict__ w0a,
    const float* __restrict__ w0b, const float* __restrict__ w1,
    __hip_bfloat16* __restrict__ a00, __hip_bfloat16* __restrict__ b00,
    __hip_bfloat16* __restrict__ g10,
    __hip_bfloat16* __restrict__ a01, __hip_bfloat16* __restrict__ b01,
    __hip_bfloat16* __restrict__ g11,
    float* __restrict__ r1v)
{
    float sw[6][5];
    softmax5(w0a + 0, sw[0]); softmax5(w0b + 0, sw[1]); softmax5(w1 + 0, sw[2]);
    softmax5(w0a + 5, sw[3]); softmax5(w0b + 5, sw[4]); softmax5(w1 + 5, sw[5]);

    const int i  = blockIdx.x;
    const int t  = threadIdx.x;
    const int j0 = t * 8;
    float acc[6][8] = {};
    if (i < NVALID && j0 < NVALID) {
        #pragma unroll
        for (int e = 0; e < 5; ++e) {
            const float* Ae = A + (size_t)e * 9000000 + (size_t)i * 3000 + j0;
            float4 v0 = *reinterpret_cast<const float4*>(Ae);
            float4 v1 = *reinterpret_cast<const float4*>(Ae + 4);
            float x[8] = { v0.x, v0.y, v0.z, v0.w, v1.x, v1.y, v1.z, v1.w };
            #pragma unroll
            for (int m = 0; m < 6; ++m) {
                float se = sw[m][e];
                #pragma unroll
                for (int u = 0; u < 8; ++u) acc[m][u] += se * x[u];
            }
        }
    }
    __hip_bfloat16* dsts[6] = { a00, b00, g10, a01, b01, g11 };
    const size_t base = (size_t)i * NPAD + j0;
    float rs[4];
    #pragma unroll
    for (int m = 0; m < 6; ++m) {
        __align__(16) __hip_bfloat16 h[8];
        float s = 0.f;
        #pragma unroll
        for (int u = 0; u < 8; ++u) {
            h[u] = __float2bfloat16(acc[m][u]);
            s += b2f(h[u]);
        }
        *reinterpret_cast<uint4*>(&dsts[m][base]) = *reinterpret_cast<const uint4*>(h);
        if (m == 1) rs[0] = s; else if (m == 2) rs[1] = s;
        else if (m == 4) rs[2] = s; else if (m == 5) rs[3] = s;
    }
    __shared__ float red[6][4];
    #pragma unroll
    for (int q = 0; q < 4; ++q) {
        float s = rs[q];
        #pragma unroll
        for (int off = 32; off > 0; off >>= 1) s += __shfl_down(s, off);
        if ((t & 63) == 0) red[t >> 6][q] = s;
    }
    __syncthreads();
    if (t == 0) {
        #pragma unroll
        for (int q = 0; q < 4; ++q) {
            float s = red[0][q] + red[1][q] + red[2][q]
                    + red[3][q] + red[4][q] + red[5][q];
            r1v[(size_t)q * NPAD + i] = s;
        }
    }
}

// ---------------------------------------------------------------- batched degree matvecs
__global__ __launch_bounds__(256) void matvec_degA(
    const __hip_bfloat16* __restrict__ a0_0, const __hip_bfloat16* __restrict__ a0_1,
    const __hip_bfloat16* __restrict__ b0_0, const __hip_bfloat16* __restrict__ b0_1,
    const float* __restrict__ r1v,
    float* __restrict__ dinv2, float* __restrict__ mv12)
{
    const int y = blockIdx.y;
    const __hip_bfloat16* M = (y == 0) ? a0_0 : (y == 1) ? a0_1 : (y == 2) ? b0_0 : b0_1;
    const float* v = (y == 0) ? r1v : (y == 1) ? r1v + 2 * NPAD
                   : (y == 2) ? r1v + NPAD : r1v + 3 * NPAD;
    const size_t i = blockIdx.x;
    const int t = threadIdx.x;
    const __hip_bfloat16* row = M + i * NPAD;
    float s = 0.f;
    for (int k = t * 8; k < NPAD; k += 2048) {
        uint4 u = *reinterpret_cast<const uint4*>(&row[k]);
        const unsigned short* us = reinterpret_cast<const unsigned short*>(&u);
        #pragma unroll
        for (int e = 0; e < 8; ++e)
            s += __uint_as_float(((unsigned int)us[e]) << 16) * v[k + e];
    }
    #pragma unroll
    for (int off = 32; off > 0; off >>= 1) s += __shfl_down(s, off);
    __shared__ float red[4];
    if ((t & 63) == 0) red[t >> 6] = s;
    __syncthreads();
    if (t == 0) {
        float tot = red[0] + red[1] + red[2] + red[3];
        if (y < 2) dinv2[(size_t)y * NPAD + i] = 1.f / (tot + 1.f);
        else       mv12[(size_t)(y - 2) * NPAD + i] = tot;
    }
}

__global__ __launch_bounds__(256) void matvec_degB(
    const __hip_bfloat16* __restrict__ a0_0, const __hip_bfloat16* __restrict__ a0_1,
    const float* __restrict__ mv12, const float* __restrict__ dinv2,
    const float* __restrict__ r1v, float* __restrict__ rsv2)
{
    const int c = blockIdx.y;
    const __hip_bfloat16* M = c ? a0_1 : a0_0;
    const float* v = mv12 + (size_t)c * NPAD;
    const float* add = r1v + (size_t)(2 * c + 1) * NPAD;
    const size_t i = blockIdx.x;
    const int t = threadIdx.x;
    const __hip_bfloat16* row = M + i * NPAD;
    float s = 0.f;
    for (int k = t * 8; k < NPAD; k += 2048) {
        uint4 u = *reinterpret_cast<const uint4*>(&row[k]);
        const unsigned short* us = reinterpret_cast<const unsigned short*>(&u);
        #pragma unroll
        for (int e = 0; e < 8; ++e)
            s += __uint_as_float(((unsigned int)us[e]) << 16) * v[k + e];
    }
    #pragma unroll
    for (int off = 32; off > 0; off >>= 1) s += __shfl_down(s, off);
    __shared__ float red[4];
    if ((t & 63) == 0) red[t >> 6] = s;
    __syncthreads();
    if (t == 0) {
        float tot = red[0] + red[1] + red[2] + red[3];
        rsv2[(size_t)c * NPAD + i] =
            rsqrtf(dinv2[(size_t)c * NPAD + i] * (tot + add[i]) + 2.f);
    }
}

// ---------------------------------------------------------------- DTI degree + scale (f32)
__global__ __launch_bounds__(256) void rowdeg_f32(
    const float* __restrict__ src, float* __restrict__ outv)
{
    const int i = blockIdx.x, t = threadIdx.x;
    float s = 0.f;
    if (i < NVALID) {
        const float* row = src + (size_t)i * 3000;
        for (int j4 = t; j4 < 750; j4 += 256) {
            float4 v = *reinterpret_cast<const float4*>(row + j4 * 4);
            s += v.x + v.y + v.z + v.w;
        }
    }
    #pragma unroll
    for (int off = 32; off > 0; off >>= 1) s += __shfl_down(s, off);
    __shared__ float red[4];
    if ((t & 63) == 0) red[t >> 6] = s;
    __syncthreads();
    if (t == 0) {
        float tot = red[0] + red[1] + red[2] + red[3];
        outv[i] = rsqrtf(tot + 2.f);
    }
}

__global__ __launch_bounds__(256) void scale_cast_f32(
    const float* __restrict__ src, int lds_, int nvalid,
    const float* __restrict__ vec, __hip_bfloat16* __restrict__ dst)
{
    const int i = blockIdx.y;
    const int j0 = (blockIdx.x * 256 + threadIdx.x) * 4;
    const float vi = vec[i];
    float v[4];
    if (i < nvalid && j0 + 3 < nvalid) {
        float4 f = *reinterpret_cast<const float4*>(src + (size_t)i * lds_ + j0);
        v[0] = f.x; v[1] = f.y; v[2] = f.z; v[3] = f.w;
    } else {
        #pragma unroll
        for (int u = 0; u < 4; ++u) {
            int j = j0 + u;
            v[u] = (i < nvalid && j < nvalid) ? src[(size_t)i * lds_ + j] : 0.f;
        }
    }
    #pragma unroll
    for (int u = 0; u < 4; ++u) {
        int j = j0 + u;
        if (j == i && i < nvalid) v[u] += 2.f;
        v[u] *= vi * vec[j];
    }
    __align__(8) __hip_bfloat16 h[4];
    #pragma unroll
    for (int u = 0; u < 4; ++u) h[u] = __float2bfloat16(v[u]);
    *reinterpret_cast<uint2*>(&dst[(size_t)i * NPAD + j0]) =
        *reinterpret_cast<const uint2*>(h);
}

// ---------------------------------------------------------------- transpose feature (f32 -> bf16^T)
__global__ __launch_bounds__(256) void transpose_feat(
    const float* __restrict__ X, int nvalid, __hip_bfloat16* __restrict__ XT)
{
    __shared__ float Ts[32][33];
    const int k0 = blockIdx.x * 32, n0 = blockIdx.y * 32;
    const int t = threadIdx.x, tr = t >> 5, tc = t & 31;
    #pragma unroll
    for (int p = 0; p < 4; ++p) {
        int k = k0 + tr + p * 8;
        Ts[tr + p * 8][tc] = (k < nvalid) ? X[(size_t)k * 128 + n0 + tc] : 0.f;
    }
    __syncthreads();
    #pragma unroll
    for (int p = 0; p < 4; ++p) {
        int n = tr + p * 8;
        XT[(size_t)(n0 + n) * NPAD + k0 + tc] = __float2bfloat16(Ts[tc][n]);
    }
}

// ---------------------------------------------------------------- W0T_c[f][i] = rsv_c[i] * XTF[f][i]
__global__ __launch_bounds__(256) void scale_colsT2(
    const __hip_bfloat16* __restrict__ XT, const float* __restrict__ rsv2,
    __hip_bfloat16* __restrict__ W0T_0, __hip_bfloat16* __restrict__ W0T_1)
{
    const int c = blockIdx.z;
    const float* s = rsv2 + (size_t)c * NPAD;
    __hip_bfloat16* W0T = c ? W0T_1 : W0T_0;
    const int f = blockIdx.y;
    const int k0 = (blockIdx.x * 256 + threadIdx.x) * 8;
    if (k0 >= NPAD) return;
    uint4 u = *reinterpret_cast<const uint4*>(&XT[(size_t)f * NPAD + k0]);
    const unsigned short* us = reinterpret_cast<const unsigned short*>(&u);
    __align__(16) __hip_bfloat16 h[8];
    #pragma unroll
    for (int e = 0; e < 8; ++e) {
        float x = __uint_as_float(((unsigned int)us[e]) << 16);
        h[e] = __float2bfloat16(x * s[k0 + e]);
    }
    *reinterpret_cast<uint4*>(&W0T[(size_t)f * NPAD + k0]) =
        *reinterpret_cast<const uint4*>(h);
}

// ---------------------------------------------------------------- batched panel GEMM (T-layout)
// C_panel[f][n] = sum_k P[f][k] * M[n][k].  P: [128][NPAD], M: [NPAD][NPAD], both K-contig.
// grid (24 n-tiles, 1, NB*ZSPLIT); writes bf16 partial at slot b, z-chunk zz.
__global__ __launch_bounds__(256, 3) void gemm_pan_batch(
    const __hip_bfloat16* __restrict__ P0, const __hip_bfloat16* __restrict__ M0,
    const __hip_bfloat16* __restrict__ P1, const __hip_bfloat16* __restrict__ M1,
    const __hip_bfloat16* __restrict__ P2, const __hip_bfloat16* __restrict__ M2,
    __hip_bfloat16* __restrict__ part)
{
    const int b  = blockIdx.z / ZSPLIT;
    const int zz = blockIdx.z % ZSPLIT;
    const __hip_bfloat16* P = (b == 0) ? P0 : (b == 1) ? P1 : P2;
    const __hip_bfloat16* M = (b == 0) ? M0 : (b == 1) ? M1 : M2;
    __hip_bfloat16* C = part + (size_t)b * SLOT + (size_t)zz * PSTRIDE;

    __shared__ __align__(16) __hip_bfloat16 As[128 * 32];
    __shared__ __align__(16) __hip_bfloat16 Bs[128 * 32];
    const int t = threadIdx.x;
    const int lane = t & 63;
    const int w = t >> 6;
    const int wm = w >> 1, wn = w & 1;
    const int tn = blockIdx.x;              // big-matrix row tile
    const int kbeg = zz * KCHUNK;

    const int srow = lane >> 2;
    const int skg  = (lane & 3) * 8;
    const __hip_bfloat16* Ag = P + (size_t)(w * 32 + srow) * NPAD + skg;
    const __hip_bfloat16* Bg = M + (size_t)(tn * 128 + w * 32 + srow) * NPAD + skg;
    __hip_bfloat16* Al0 = &As[w * 1024];
    __hip_bfloat16* Al1 = &As[w * 1024 + 512];
    __hip_bfloat16* Bl0 = &Bs[w * 1024];
    __hip_bfloat16* Bl1 = &Bs[w * 1024 + 512];

    floatx4 acc[4][4] = {};

    for (int k0 = kbeg; k0 < kbeg + KCHUNK; k0 += 32) {
        __syncthreads();
        gload16(Ag + k0,             Al0);
        gload16(Ag + 16 * NPAD + k0, Al1);
        gload16(Bg + k0,             Bl0);
        gload16(Bg + 16 * NPAD + k0, Bl1);
        __syncthreads();

        bf16x8 af[4], bfv[4];
        const int koff = (lane >> 4) * 8;
        #pragma unroll
        for (int mi = 0; mi < 4; ++mi)
            af[mi] = *reinterpret_cast<const bf16x8*>(
                &As[(wm * 64 + mi * 16 + (lane & 15)) * 32 + koff]);
        #pragma unroll
        for (int ni = 0; ni < 4; ++ni)
            bfv[ni] = *reinterpret_cast<const bf16x8*>(
                &Bs[(wn * 64 + ni * 16 + (lane & 15)) * 32 + koff]);
        #pragma unroll
        for (int mi = 0; mi < 4; ++mi)
            #pragma unroll
            for (int ni = 0; ni < 4; ++ni)
                acc[mi][ni] = __builtin_amdgcn_mfma_f32_16x16x32_bf16(
                    af[mi], bfv[ni], acc[mi][ni], 0, 0, 0);
    }

    const int r0 = wm * 64 + ((lane >> 4) << 2);          // f (panel row)
    const int c0 = tn * 128 + wn * 64 + (lane & 15);      // n (big-matrix row)
    #pragma unroll
    for (int mi = 0; mi < 4; ++mi)
        #pragma unroll
        for (int ni = 0; ni < 4; ++ni)
            #pragma unroll
            for (int r = 0; r < 4; ++r)
                C[(size_t)(r0 + mi * 16 + r) * NPAD + c0 + ni * 16] =
                    __float2bfloat16(acc[mi][ni][r]);
}

// ---------------------------------------------------------------- final GEMM (sigmoid epilogue)
__global__ __launch_bounds__(256, 3) void gemm_sig(
    const __hip_bfloat16* __restrict__ A, const __hip_bfloat16* __restrict__ BT,
    float* __restrict__ C, int Kchunk, int lda, int ldb, int ldc,
    int Mvalid, int Nvalid)
{
    __shared__ __align__(16) __hip_bfloat16 As[128 * 32];
    __shared__ __align__(16) __hip_bfloat16 Bs[128 * 32];
    const int t = threadIdx.x;
    const int lane = t & 63;
    const int w = t >> 6;
    const int wm = w >> 1, wn = w & 1;
    const int tm = blockIdx.y, tn = blockIdx.x;

    const int srow = lane >> 2;
    const int skg  = (lane & 3) * 8;
    const __hip_bfloat16* Ag = A  + (size_t)(tm * 128 + w * 32 + srow) * lda + skg;
    const __hip_bfloat16* Bg = BT + (size_t)(tn * 128 + w * 32 + srow) * ldb + skg;
    __hip_bfloat16* Al0 = &As[w * 1024];
    __hip_bfloat16* Al1 = &As[w * 1024 + 512];
    __hip_bfloat16* Bl0 = &Bs[w * 1024];
    __hip_bfloat16* Bl1 = &Bs[w * 1024 + 512];

    floatx4 acc[4][4] = {};

    for (int k0 = 0; k0 < Kchunk; k0 += 32) {
        __syncthreads();
        gload16(Ag + k0,            Al0);
        gload16(Ag + 16 * lda + k0, Al1);
        gload16(Bg + k0,            Bl0);
        gload16(Bg + 16 * ldb + k0, Bl1);
        __syncthreads();

        bf16x8 af[4], bfv[4];
        const int koff = (lane >> 4) * 8;
        #pragma unroll
        for (int mi = 0; mi < 4; ++mi)
            af[mi] = *reinterpret_cast<const bf16x8*>(
                &As[(wm * 64 + mi * 16 + (lane & 15)) * 32 + koff]);
        #pragma unroll
        for (int ni = 0; ni < 4; ++ni)
            bfv[ni] = *reinterpret_cast<const bf16x8*>(
                &Bs[(wn * 64 + ni * 16 + (lane & 15)) * 32 + koff]);
        #pragma unroll
        for (int mi = 0; mi < 4; ++mi)
            #pragma unroll
            for (int ni = 0; ni < 4; ++ni)
                acc[mi][ni] = __builtin_amdgcn_mfma_f32_16x16x32_bf16(
                    af[mi], bfv[ni], acc[mi][ni], 0, 0, 0);
    }

    const int r0 = tm * 128 + wm * 64 + ((lane >> 4) << 2);
    const int c0 = tn * 128 + wn * 64 + (lane & 15);
    #pragma unroll
    for (int mi = 0; mi < 4; ++mi)
        #pragma unroll
        for (int ni = 0; ni < 4; ++ni) {
            const int col = c0 + ni * 16;
            #pragma unroll
            for (int r = 0; r < 4; ++r) {
                const int row = r0 + mi * 16 + r;
                if (row < Mvalid && col < Nvalid)
                    C[(size_t)row * ldc + col] =
                        1.f / (1.f + __expf(-acc[mi][ni][r]));
            }
        }
}

// ---------------------------------------------------------------- elementwise z-sum of bf16 partials
// grid (192, NB); out[b][idx] = sum_z part[b][z][idx]; null out -> skip
__global__ __launch_bounds__(256) void reduce_sum_b(
    const __hip_bfloat16* __restrict__ part,
    __hip_bfloat16* __restrict__ O0, __hip_bfloat16* __restrict__ O1,
    __hip_bfloat16* __restrict__ O2)
{
    const int b = blockIdx.y;
    __hip_bfloat16* O = (b == 0) ? O0 : (b == 1) ? O1 : O2;
    if (!O) return;
    const __hip_bfloat16* Pp = part + (size_t)b * SLOT;
    const size_t idx = ((size_t)blockIdx.x * 256 + threadIdx.x) * 8;
    float s[8] = {};
    #pragma unroll
    for (int z = 0; z < ZSPLIT; ++z) {
        uint4 u = *reinterpret_cast<const uint4*>(&Pp[(size_t)z * PSTRIDE + idx]);
        const unsigned short* us = reinterpret_cast<const unsigned short*>(&u);
        #pragma unroll
        for (int e = 0; e < 8; ++e)
            s[e] += __uint_as_float(((unsigned int)us[e]) << 16);
    }
    __align__(16) __hip_bfloat16 h[8];
    #pragma unroll
    for (int e = 0; e < 8; ++e) h[e] = __float2bfloat16(s[e]);
    *reinterpret_cast<uint4*>(&O[idx]) = *reinterpret_cast<const uint4*>(h);
}

// ---------------------------------------------------------------- DTI: z-sum slot0 + transpose + att0 -> conv[i][f]
__global__ __launch_bounds__(256) void reduce_att_T(
    const __hip_bfloat16* __restrict__ part, const float* __restrict__ ap,
    float* __restrict__ conv)
{
    __shared__ float Ts[32][33];
    const int i0 = blockIdx.x * 32, f0 = blockIdx.y * 32;
    const int t = threadIdx.x, tr = t >> 5, tc = t & 31;
    float a0 = ap[0], a1 = ap[1], a2 = ap[2];
    float m = fmaxf(a0, fmaxf(a1, a2));
    float e0 = __expf(a0 - m), e1 = __expf(a1 - m), e2 = __expf(a2 - m);
    float att0 = e0 / (e0 + e1 + e2);
    #pragma unroll
    for (int p = 0; p < 4; ++p) {
        int f = f0 + tr + p * 8;
        float s = 0.f;
        #pragma unroll
        for (int z = 0; z < ZSPLIT; ++z)
            s += b2f(part[(size_t)z * PSTRIDE + (size_t)f * NPAD + i0 + tc]);
        Ts[tr + p * 8][tc] = s;
    }
    __syncthreads();
    #pragma unroll
    for (int p = 0; p < 4; ++p) {
        int i = i0 + tr + p * 8;
        conv[(size_t)i * 128 + f0 + tc] = att0 * Ts[tc][tr + p * 8];
    }
}

// ---------------------------------------------------------------- hop1 combine (elementwise, [f][i] layout)
// Wp_c[f][i] = s_i*( s_i*d_i*(V + Z) + 2*s_i^2 * XTF[f][i] )
__global__ __launch_bounds__(256) void combine_mid2(
    const __hip_bfloat16* __restrict__ part,
    const __hip_bfloat16* __restrict__ Z0, const __hip_bfloat16* __restrict__ Z1,
    const __hip_bfloat16* __restrict__ XTF,
    const float* __restrict__ rsv2, const float* __restrict__ dinv2,
    __hip_bfloat16* __restrict__ Wp0, __hip_bfloat16* __restrict__ Wp1)
{
    const int c = blockIdx.y;
    const __hip_bfloat16* Vp = part + (size_t)c * SLOT;
    const __hip_bfloat16* Z  = c ? Z1 : Z0;
    const float* sv = rsv2 + (size_t)c * NPAD;
    const float* dv = dinv2 + (size_t)c * NPAD;
    __hip_bfloat16* Wp = c ? Wp1 : Wp0;

    const size_t idx = ((size_t)blockIdx.x * 256 + threadIdx.x) * 8;
    const int i = (int)(idx % NPAD);   // 8 | NPAD so all 8 elems share f, consecutive i
    float s[8] = {};
    #pragma unroll
    for (int z = 0; z < ZSPLIT; ++z) {
        uint4 u = *reinterpret_cast<const uint4*>(&Vp[(size_t)z * PSTRIDE + idx]);
        const unsigned short* us = reinterpret_cast<const unsigned short*>(&u);
        #pragma unroll
        for (int e = 0; e < 8; ++e)
            s[e] += __uint_as_float(((unsigned int)us[e]) << 16);
    }
    uint4 uz = *reinterpret_cast<const uint4*>(&Z[idx]);
    uint4 ux = *reinterpret_cast<const uint4*>(&XTF[idx]);
    const unsigned short* usz = reinterpret_cast<const unsigned short*>(&uz);
    const unsigned short* usx = reinterpret_cast<const unsigned short*>(&ux);
    __align__(16) __hip_bfloat16 h[8];
    #pragma unroll
    for (int e = 0; e < 8; ++e) {
        float vsum = s[e] + __uint_as_float(((unsigned int)usz[e]) << 16);
        float x    = __uint_as_float(((unsigned int)usx[e]) << 16);
        float si = sv[i + e], di = dv[i + e];
        float out1 = si * di * vsum + 2.f * si * si * x;
        h[e] = __float2bfloat16(si * out1);
    }
    *reinterpret_cast<uint4*>(&Wp[idx]) = *reinterpret_cast<const uint4*>(h);
}

// ---------------------------------------------------------------- hop2 combine + attention (transpose into conv)
__global__ __launch_bounds__(256) void combine_att2_T(
    const __hip_bfloat16* __restrict__ part,
    const __hip_bfloat16* __restrict__ Z2_0, const __hip_bfloat16* __restrict__ Z2_1,
    const __hip_bfloat16* __restrict__ Wp0, const __hip_bfloat16* __restrict__ Wp1,
    const float* __restrict__ rsv2, const float* __restrict__ dinv2,
    const float* __restrict__ ap, float* __restrict__ conv)
{
    __shared__ float Ts[32][33];
    const int i0 = blockIdx.x * 32, f0 = blockIdx.y * 32;
    const int t = threadIdx.x, tr = t >> 5, tc = t & 31;
    float a0 = ap[0], a1 = ap[1], a2 = ap[2];
    float m = fmaxf(a0, fmaxf(a1, a2));
    float e0 = __expf(a0 - m), e1 = __expf(a1 - m), e2 = __expf(a2 - m);
    float inv = 1.f / (e0 + e1 + e2);
    float att1 = e1 * inv, att2 = e2 * inv;
    const int i = i0 + tc;
    float s0i = rsv2[i],        d0i = dinv2[i];
    float s1i = rsv2[NPAD + i], d1i = dinv2[NPAD + i];
    #pragma unroll
    for (int p = 0; p < 4; ++p) {
        int f = f0 + tr + p * 8;
        size_t fi = (size_t)f * NPAD + i;
        float v0 = b2f(Z2_0[fi]);
        float v1 = b2f(Z2_1[fi]);
        #pragma unroll
        for (int z = 0; z < ZSPLIT; ++z) {
            v0 += b2f(part[(size_t)z * PSTRIDE + fi]);
            v1 += b2f(part[SLOT + (size_t)z * PSTRIDE + fi]);
        }
        float o0 = s0i * d0i * v0 + 2.f * s0i * b2f(Wp0[fi]);
        float o1 = s1i * d1i * v1 + 2.f * s1i * b2f(Wp1[fi]);
        Ts[tr + p * 8][tc] = att1 * o0 + att2 * o1;
    }
    __syncthreads();
    #pragma unroll
    for (int p = 0; p < 4; ++p) {
        int i2 = i0 + tr + p * 8;
        conv[(size_t)i2 * 128 + f0 + tc] += Ts[tc][tr + p * 8];
    }
}

// ---------------------------------------------------------------- final split+cast
__global__ __launch_bounds__(256) void cast_split(
    const float* __restrict__ acc, __hip_bfloat16* __restrict__ dF,
    __hip_bfloat16* __restrict__ pF)
{
    const int idx = blockIdx.x * 256 + threadIdx.x;
    if (idx < 1024 * 128) {
        int r = idx >> 7;
        dF[idx] = __float2bfloat16(r < 1000 ? acc[idx] : 0.f);
    } else {
        int j = idx - 1024 * 128;
        int r = j >> 7;
        pF[j] = __float2bfloat16(r < 2000 ? acc[(size_t)(1000 + r) * 128 + (j & 127)] : 0.f);
    }
}

// ================================================================ launch
extern "C" void kernel_launch(void* const* d_in, const int* in_sizes, int n_in,
                              void* d_out, int out_size, void* d_ws, size_t ws_size,
                              hipStream_t stream)
{
    const float* A     = (const float*)d_in[0];
    const float* DTI   = (const float*)d_in[1];
    const float* drugS = (const float*)d_in[2];
    const float* protS = (const float*)d_in[3];
    const float* w0a   = (const float*)d_in[4];
    const float* w0b   = (const float*)d_in[5];
    const float* w1g   = (const float*)d_in[6];
    const float* ap    = (const float*)d_in[7];
    const float* wd1 = (const float*)d_in[10]; const float* bd1 = (const float*)d_in[11];
    const float* wd2 = (const float*)d_in[12]; const float* bd2 = (const float*)d_in[13];
    const float* wd3 = (const float*)d_in[14]; const float* bd3 = (const float*)d_in[15];
    const float* wp1 = (const float*)d_in[16]; const float* bp1 = (const float*)d_in[17];
    const float* wp2 = (const float*)d_in[18]; const float* bp2 = (const float*)d_in[19];
    const float* wp3 = (const float*)d_in[20]; const float* bp3 = (const float*)d_in[21];
    float* out = (float*)d_out;

    const size_t SQ_BF  = (size_t)NPAD * NPAD * 2;
    const size_t PAN_BF = (size_t)128 * NPAD * 2;
    char* p = (char*)d_ws;
    auto alloc = [&](size_t sz) { char* r = p; p += (sz + 255) & ~(size_t)255; return r; };
    __hip_bfloat16* sdti = (__hip_bfloat16*)alloc(SQ_BF);
    __hip_bfloat16* a0c[2], *b0c[2], *g1c[2];
    for (int c = 0; c < 2; ++c) {
        a0c[c] = (__hip_bfloat16*)alloc(SQ_BF);
        b0c[c] = (__hip_bfloat16*)alloc(SQ_BF);
        g1c[c] = (__hip_bfloat16*)alloc(SQ_BF);
    }
    __hip_bfloat16* part = (__hip_bfloat16*)alloc((size_t)3 * SLOT * 2);
    float* r1v   = (float*)alloc((size_t)4 * NPAD * 4);
    float* dinv2 = (float*)alloc((size_t)2 * NPAD * 4);
    float* mv12  = (float*)alloc((size_t)2 * NPAD * 4);
    float* rsv2  = (float*)alloc((size_t)2 * NPAD * 4);
    float* degv  = (float*)alloc((size_t)NPAD * 4);
    float* fb    = (float*)alloc((size_t)NPAD * 128 * 4);
    float* conv  = (float*)alloc((size_t)NPAD * 128 * 4);
    __hip_bfloat16* XTF  = (__hip_bfloat16*)alloc(PAN_BF);
    __hip_bfloat16* XT2  = (__hip_bfloat16*)alloc(PAN_BF);
    __hip_bfloat16* W0T_0 = (__hip_bfloat16*)alloc(PAN_BF);
    __hip_bfloat16* W0T_1 = (__hip_bfloat16*)alloc(PAN_BF);
    __hip_bfloat16* Z_0  = (__hip_bfloat16*)alloc(PAN_BF);   // also Z2_0
    __hip_bfloat16* Z_1  = (__hip_bfloat16*)alloc(PAN_BF);   // also Z2_1
    __hip_bfloat16* U_0  = (__hip_bfloat16*)alloc(PAN_BF);   // also U2_0
    __hip_bfloat16* U_1  = (__hip_bfloat16*)alloc(PAN_BF);   // also U2_1
    __hip_bfloat16* Wp_0 = (__hip_bfloat16*)alloc(PAN_BF);
    __hip_bfloat16* Wp_1 = (__hip_bfloat16*)alloc(PAN_BF);
    __hip_bfloat16* dF = (__hip_bfloat16*)alloc((size_t)1024 * 128 * 2);
    __hip_bfloat16* pF = (__hip_bfloat16*)alloc((size_t)2048 * 128 * 2);
    if ((size_t)(p - (char*)d_ws) > ws_size) return;  // fail loud if ws too small

    // ---- fused MLPs -> fb; transpose
    mlp_fused<<<375, 256, 0, stream>>>(drugS, protS,
        wd1, bd1, wd2, bd2, wd3, bd3, wp1, bp1, wp2, bp2, wp3, bp3, fb);
    transpose_feat<<<dim3(96, 4), 256, 0, stream>>>(fb, 3000, XTF);

    // ---- gtconv (full-row blocks, fused rowsums)
    gtconv_fused<<<NPAD, 384, 0, stream>>>(A, w0a, w0b, w1g,
        a0c[0], b0c[0], g1c[0], a0c[1], b0c[1], g1c[1], r1v);

    // ---- DTI normalize
    rowdeg_f32<<<NPAD, 256, 0, stream>>>(DTI, degv);
    scale_cast_f32<<<dim3(3, NPAD), 256, 0, stream>>>(DTI, 3000, 3000, degv, sdti);

    // ---- batched degree matvecs + W0T
    matvec_degA<<<dim3(NPAD, 4), 256, 0, stream>>>(a0c[0], a0c[1], b0c[0], b0c[1],
        r1v, dinv2, mv12);
    matvec_degB<<<dim3(NPAD, 2), 256, 0, stream>>>(a0c[0], a0c[1], mv12, dinv2, r1v, rsv2);
    scale_colsT2<<<dim3(2, 128, 2), 256, 0, stream>>>(XTF, rsv2, W0T_0, W0T_1);

    // ---- S1: panels {XTF x sdti, W0T_0 x g1_0, W0T_1 x g1_1}
    gemm_pan_batch<<<dim3(24, 1, 3 * ZSPLIT), 256, 0, stream>>>(
        XTF, sdti, W0T_0, g1c[0], W0T_1, g1c[1], part);
    reduce_sum_b<<<dim3(192, 3), 256, 0, stream>>>(part, XT2, Z_0, Z_1);

    // ---- S2: {XT2 x sdti, Z_0 x b0_0, Z_1 x b0_1}
    gemm_pan_batch<<<dim3(24, 1, 3 * ZSPLIT), 256, 0, stream>>>(
        XT2, sdti, Z_0, b0c[0], Z_1, b0c[1], part);
    reduce_att_T<<<dim3(96, 4), 256, 0, stream>>>(part, ap, conv);          // DTI -> conv
    reduce_sum_b<<<dim3(192, 2), 256, 0, stream>>>(part + SLOT, U_0, U_1, nullptr);

    // ---- S3: {U_0 x a0_0, U_1 x a0_1}; hop1 combine -> Wp (keeps Z panels live)
    gemm_pan_batch<<<dim3(24, 1, 2 * ZSPLIT), 256, 0, stream>>>(
        U_0, a0c[0], U_1, a0c[1], nullptr, nullptr, part);
    combine_mid2<<<dim3(192, 2), 256, 0, stream>>>(part, Z_0, Z_1, XTF,
        rsv2, dinv2, Wp_0, Wp_1);

    // ---- S4..S6: hop2 (Z/U buffers reused as Z2/U2)
    gemm_pan_batch<<<dim3(24, 1, 2 * ZSPLIT), 256, 0, stream>>>(
        Wp_0, g1c[0], Wp_1, g1c[1], nullptr, nullptr, part);
    reduce_sum_b<<<dim3(192, 2), 256, 0, stream>>>(part, Z_0, Z_1, nullptr);
    gemm_pan_batch<<<dim3(24, 1, 2 * ZSPLIT), 256, 0, stream>>>(
        Z_0, b0c[0], Z_1, b0c[1], nullptr, nullptr, part);
    reduce_sum_b<<<dim3(192, 2), 256, 0, stream>>>(part, U_0, U_1, nullptr);
    gemm_pan_batch<<<dim3(24, 1, 2 * ZSPLIT), 256, 0, stream>>>(
        U_0, a0c[0], U_1, a0c[1], nullptr, nullptr, part);
    combine_att2_T<<<dim3(96, 4), 256, 0, stream>>>(part, Z_0, Z_1, Wp_0, Wp_1,
        rsv2, dinv2, ap, conv);

    // ---- final: sigmoid(drug @ prot^T)
    cast_split<<<1536, 256, 0, stream>>>(conv, dF, pF);
    gemm_sig<<<dim3(16, 8), 256, 0, stream>>>(dF, pF, out, 128, 128, 128, 2000, 1000, 2000);
}

// Round 12
// 256.223 us; speedup vs baseline: 1.1636x; 1.0434x over previous
//
#include <hip/hip_runtime.h>
#include <hip/hip_bf16.h>

typedef __attribute__((ext_vector_type(8))) __bf16 bf16x8;
typedef __attribute__((ext_vector_type(4))) float floatx4;

#define NVALID 3000
#define NPAD   3072
#define FEA    128
#define ZSPLIT 8
#define KCHUNK 384
#define PSTRIDE 393216   // 128*NPAD (panel elements)
#define SLOT   ((size_t)ZSPLIT * PSTRIDE)

// async global->LDS, 16B per lane
__device__ __forceinline__ void gload16(const void* g, void* l) {
    __builtin_amdgcn_global_load_lds(
        (const __attribute__((address_space(1))) void*)g,
        (__attribute__((address_space(3))) void*)l,
        16, 0, 0);
}

__device__ __forceinline__ float b2f(__hip_bfloat16 h) { return __bfloat162float(h); }

// ---------------------------------------------------------------- softmax5
__device__ __forceinline__ void softmax5(const float* __restrict__ w, float* s)
{
    float m = w[0];
    #pragma unroll
    for (int e = 1; e < 5; ++e) m = fmaxf(m, w[e]);
    float sum = 0.f;
    #pragma unroll
    for (int e = 0; e < 5; ++e) { s[e] = __expf(w[e] - m); sum += s[e]; }
    float r = 1.f / sum;
    #pragma unroll
    for (int e = 0; e < 5; ++e) s[e] *= r;
}

// ================================================================ L0: head fused
// blocks [0,NPAD): gtconv row; [NPAD,2*NPAD): DTI rowdeg; [2*NPAD, 2*NPAD+375): MLP
__global__ __launch_bounds__(384) void head_fused(
    const float* __restrict__ A, const float* __restrict__ w0a,
    const float* __restrict__ w0b, const float* __restrict__ w1,
    __hip_bfloat16* __restrict__ a00, __hip_bfloat16* __restrict__ b00,
    __hip_bfloat16* __restrict__ g10,
    __hip_bfloat16* __restrict__ a01, __hip_bfloat16* __restrict__ b01,
    __hip_bfloat16* __restrict__ g11,
    float* __restrict__ r1v,
    const float* __restrict__ DTI, float* __restrict__ degv,
    const float* __restrict__ Xd, const float* __restrict__ Xp,
    const float* __restrict__ Wd1, const float* __restrict__ bd1,
    const float* __restrict__ Wd2, const float* __restrict__ bd2,
    const float* __restrict__ Wd3, const float* __restrict__ bd3,
    const float* __restrict__ Wp1, const float* __restrict__ bp1,
    const float* __restrict__ Wp2, const float* __restrict__ bp2,
    const float* __restrict__ Wp3, const float* __restrict__ bp3,
    float* __restrict__ Y)
{
    const int bid = blockIdx.x;
    const int t = threadIdx.x;

    if (bid < NPAD) {
        // ---------------- gtconv (full row, fused rowsums)
        float sw[6][5];
        softmax5(w0a + 0, sw[0]); softmax5(w0b + 0, sw[1]); softmax5(w1 + 0, sw[2]);
        softmax5(w0a + 5, sw[3]); softmax5(w0b + 5, sw[4]); softmax5(w1 + 5, sw[5]);

        const int i  = bid;
        const int j0 = t * 8;
        float acc[6][8] = {};
        if (i < NVALID && j0 < NVALID) {
            #pragma unroll
            for (int e = 0; e < 5; ++e) {
                const float* Ae = A + (size_t)e * 9000000 + (size_t)i * 3000 + j0;
                float4 v0 = *reinterpret_cast<const float4*>(Ae);
                float4 v1 = *reinterpret_cast<const float4*>(Ae + 4);
                float x[8] = { v0.x, v0.y, v0.z, v0.w, v1.x, v1.y, v1.z, v1.w };
                #pragma unroll
                for (int m = 0; m < 6; ++m) {
                    float se = sw[m][e];
                    #pragma unroll
                    for (int u = 0; u < 8; ++u) acc[m][u] += se * x[u];
                }
            }
        }
        __hip_bfloat16* dsts[6] = { a00, b00, g10, a01, b01, g11 };
        const size_t base = (size_t)i * NPAD + j0;
        float rs[4];
        #pragma unroll
        for (int m = 0; m < 6; ++m) {
            __align__(16) __hip_bfloat16 h[8];
            float s = 0.f;
            #pragma unroll
            for (int u = 0; u < 8; ++u) {
                h[u] = __float2bfloat16(acc[m][u]);
                s += b2f(h[u]);
            }
            *reinterpret_cast<uint4*>(&dsts[m][base]) = *reinterpret_cast<const uint4*>(h);
            if (m == 1) rs[0] = s; else if (m == 2) rs[1] = s;
            else if (m == 4) rs[2] = s; else if (m == 5) rs[3] = s;
        }
        __shared__ float redg[6][4];
        #pragma unroll
        for (int q = 0; q < 4; ++q) {
            float s = rs[q];
            #pragma unroll
            for (int off = 32; off > 0; off >>= 1) s += __shfl_down(s, off);
            if ((t & 63) == 0) redg[t >> 6][q] = s;
        }
        __syncthreads();
        if (t == 0) {
            #pragma unroll
            for (int q = 0; q < 4; ++q) {
                float s = redg[0][q] + redg[1][q] + redg[2][q]
                        + redg[3][q] + redg[4][q] + redg[5][q];
                r1v[(size_t)q * NPAD + i] = s;
            }
        }
    } else if (bid < 2 * NPAD) {
        // ---------------- DTI row degree
        const int i = bid - NPAD;
        float s = 0.f;
        if (i < NVALID) {
            const float* row = DTI + (size_t)i * 3000;
            for (int j4 = t; j4 < 750; j4 += 384) {
                float4 v = *reinterpret_cast<const float4*>(row + j4 * 4);
                s += v.x + v.y + v.z + v.w;
            }
        }
        #pragma unroll
        for (int off = 32; off > 0; off >>= 1) s += __shfl_down(s, off);
        __shared__ float redd[6];
        if ((t & 63) == 0) redd[t >> 6] = s;
        __syncthreads();
        if (t == 0) {
            float tot = redd[0] + redd[1] + redd[2] + redd[3] + redd[4] + redd[5];
            degv[i] = rsqrtf(tot + 2.f);
        }
    } else {
        // ---------------- MLP (3 layers); threads >=256 idle outside barriers
        const int blk = bid - 2 * NPAD;
        const bool isP = blk >= 125;
        const float* X  = isP ? Xp : Xd;
        const float* W1 = isP ? Wp1 : Wd1; const float* b1 = isP ? bp1 : bd1;
        const float* W2 = isP ? Wp2 : Wd2; const float* b2 = isP ? bp2 : bd2;
        const float* W3 = isP ? Wp3 : Wd3; const float* b3 = isP ? bp3 : bd3;
        const int m0loc = (isP ? (blk - 125) : blk) * 8;
        const int m0out = blk * 8;

        __shared__ float S0[8][128], S1m[8][128];
        for (int s2 = t; s2 < 1024; s2 += 384) {
            int r = s2 >> 7, ii = s2 & 127;
            S0[r][ii] = X[(size_t)(m0loc + r) * 128 + ii];
        }
        __syncthreads();
        const int o = t & 127, rh = t >> 7;
        if (t < 256) {
            float a0 = 0.f, a1 = 0.f, a2 = 0.f, a3 = 0.f;
            const float* wr = W1 + (size_t)o * 128;
            for (int i = 0; i < 128; ++i) {
                float w = wr[i];
                a0 += S0[rh + 0][i] * w; a1 += S0[rh + 2][i] * w;
                a2 += S0[rh + 4][i] * w; a3 += S0[rh + 6][i] * w;
            }
            float bo = b1[o];
            S1m[rh + 0][o] = fmaxf(a0 + bo, 0.f);
            S1m[rh + 2][o] = fmaxf(a1 + bo, 0.f);
            S1m[rh + 4][o] = fmaxf(a2 + bo, 0.f);
            S1m[rh + 6][o] = fmaxf(a3 + bo, 0.f);
        }
        __syncthreads();
        if (t < 256) {
            float a0 = 0.f, a1 = 0.f, a2 = 0.f, a3 = 0.f;
            const float* wr = W2 + (size_t)o * 128;
            for (int i = 0; i < 128; ++i) {
                float w = wr[i];
                a0 += S1m[rh + 0][i] * w; a1 += S1m[rh + 2][i] * w;
                a2 += S1m[rh + 4][i] * w; a3 += S1m[rh + 6][i] * w;
            }
            float bo = b2[o];
            S0[rh + 0][o] = fmaxf(a0 + bo, 0.f);
            S0[rh + 2][o] = fmaxf(a1 + bo, 0.f);
            S0[rh + 4][o] = fmaxf(a2 + bo, 0.f);
            S0[rh + 6][o] = fmaxf(a3 + bo, 0.f);
        }
        __syncthreads();
        if (t < 256) {
            float a0 = 0.f, a1 = 0.f, a2 = 0.f, a3 = 0.f;
            const float* wr = W3 + (size_t)o * 128;
            for (int i = 0; i < 128; ++i) {
                float w = wr[i];
                a0 += S0[rh + 0][i] * w; a1 += S0[rh + 2][i] * w;
                a2 += S0[rh + 4][i] * w; a3 += S0[rh + 6][i] * w;
            }
            float bo = b3[o];
            Y[(size_t)(m0out + rh + 0) * 128 + o] = fmaxf(a0 + bo, 0.f);
            Y[(size_t)(m0out + rh + 2) * 128 + o] = fmaxf(a1 + bo, 0.f);
            Y[(size_t)(m0out + rh + 4) * 128 + o] = fmaxf(a2 + bo, 0.f);
            Y[(size_t)(m0out + rh + 6) * 128 + o] = fmaxf(a3 + bo, 0.f);
        }
    }
}

// ================================================================ L1: mid fused (256 thr)
// blocks [0,384): transpose_feat; [384,9600): DTI scale_cast; [9600,21888): matvec_degA
__global__ __launch_bounds__(256) void mid_fused(
    const float* __restrict__ fb, __hip_bfloat16* __restrict__ XTF,
    const float* __restrict__ DTI, const float* __restrict__ degv,
    __hip_bfloat16* __restrict__ sdti,
    const __hip_bfloat16* __restrict__ a0_0, const __hip_bfloat16* __restrict__ a0_1,
    const __hip_bfloat16* __restrict__ b0_0, const __hip_bfloat16* __restrict__ b0_1,
    const float* __restrict__ r1v,
    float* __restrict__ dinv2, float* __restrict__ mv12)
{
    const int bid = blockIdx.x;
    const int t = threadIdx.x;

    if (bid < 384) {
        // ---------------- transpose_feat
        __shared__ float Ts[32][33];
        const int k0 = (bid % 96) * 32, n0 = (bid / 96) * 32;
        const int tr = t >> 5, tc = t & 31;
        #pragma unroll
        for (int p = 0; p < 4; ++p) {
            int k = k0 + tr + p * 8;
            Ts[tr + p * 8][tc] = (k < NVALID) ? fb[(size_t)k * 128 + n0 + tc] : 0.f;
        }
        __syncthreads();
        #pragma unroll
        for (int p = 0; p < 4; ++p) {
            int n = tr + p * 8;
            XTF[(size_t)(n0 + n) * NPAD + k0 + tc] = __float2bfloat16(Ts[tc][n]);
        }
    } else if (bid < 9600) {
        // ---------------- DTI scale + cast
        const int r = bid - 384;
        const int i = r / 3;
        const int j0 = ((r % 3) * 256 + t) * 4;
        const float vi = degv[i];
        float v[4];
        if (i < NVALID && j0 + 3 < NVALID) {
            float4 f = *reinterpret_cast<const float4*>(DTI + (size_t)i * 3000 + j0);
            v[0] = f.x; v[1] = f.y; v[2] = f.z; v[3] = f.w;
        } else {
            #pragma unroll
            for (int u = 0; u < 4; ++u) {
                int j = j0 + u;
                v[u] = (i < NVALID && j < NVALID) ? DTI[(size_t)i * 3000 + j] : 0.f;
            }
        }
        #pragma unroll
        for (int u = 0; u < 4; ++u) {
            int j = j0 + u;
            if (j == i && i < NVALID) v[u] += 2.f;
            v[u] *= vi * degv[j];
        }
        __align__(8) __hip_bfloat16 h[4];
        #pragma unroll
        for (int u = 0; u < 4; ++u) h[u] = __float2bfloat16(v[u]);
        *reinterpret_cast<uint2*>(&sdti[(size_t)i * NPAD + j0]) =
            *reinterpret_cast<const uint2*>(h);
    } else {
        // ---------------- matvec_degA
        const int r = bid - 9600;
        const int y = r / NPAD;
        const size_t i = r % NPAD;
        const __hip_bfloat16* M = (y == 0) ? a0_0 : (y == 1) ? a0_1
                                : (y == 2) ? b0_0 : b0_1;
        const float* v = (y == 0) ? r1v : (y == 1) ? r1v + 2 * NPAD
                       : (y == 2) ? r1v + NPAD : r1v + 3 * NPAD;
        const __hip_bfloat16* row = M + i * NPAD;
        float s = 0.f;
        for (int k = t * 8; k < NPAD; k += 2048) {
            uint4 u = *reinterpret_cast<const uint4*>(&row[k]);
            const unsigned short* us = reinterpret_cast<const unsigned short*>(&u);
            #pragma unroll
            for (int e = 0; e < 8; ++e)
                s += __uint_as_float(((unsigned int)us[e]) << 16) * v[k + e];
        }
        #pragma unroll
        for (int off = 32; off > 0; off >>= 1) s += __shfl_down(s, off);
        __shared__ float red[4];
        if ((t & 63) == 0) red[t >> 6] = s;
        __syncthreads();
        if (t == 0) {
            float tot = red[0] + red[1] + red[2] + red[3];
            if (y < 2) dinv2[(size_t)y * NPAD + i] = 1.f / (tot + 1.f);
            else       mv12[(size_t)(y - 2) * NPAD + i] = tot;
        }
    }
}

// ---------------------------------------------------------------- matvec_degB
__global__ __launch_bounds__(256) void matvec_degB(
    const __hip_bfloat16* __restrict__ a0_0, const __hip_bfloat16* __restrict__ a0_1,
    const float* __restrict__ mv12, const float* __restrict__ dinv2,
    const float* __restrict__ r1v, float* __restrict__ rsv2)
{
    const int c = blockIdx.y;
    const __hip_bfloat16* M = c ? a0_1 : a0_0;
    const float* v = mv12 + (size_t)c * NPAD;
    const float* add = r1v + (size_t)(2 * c + 1) * NPAD;
    const size_t i = blockIdx.x;
    const int t = threadIdx.x;
    const __hip_bfloat16* row = M + i * NPAD;
    float s = 0.f;
    for (int k = t * 8; k < NPAD; k += 2048) {
        uint4 u = *reinterpret_cast<const uint4*>(&row[k]);
        const unsigned short* us = reinterpret_cast<const unsigned short*>(&u);
        #pragma unroll
        for (int e = 0; e < 8; ++e)
            s += __uint_as_float(((unsigned int)us[e]) << 16) * v[k + e];
    }
    #pragma unroll
    for (int off = 32; off > 0; off >>= 1) s += __shfl_down(s, off);
    __shared__ float red[4];
    if ((t & 63) == 0) red[t >> 6] = s;
    __syncthreads();
    if (t == 0) {
        float tot = red[0] + red[1] + red[2] + red[3];
        rsv2[(size_t)c * NPAD + i] =
            rsqrtf(dinv2[(size_t)c * NPAD + i] * (tot + add[i]) + 2.f);
    }
}

// ---------------------------------------------------------------- W0T_c[f][i] = rsv_c[i] * XTF[f][i]
__global__ __launch_bounds__(256) void scale_colsT2(
    const __hip_bfloat16* __restrict__ XT, const float* __restrict__ rsv2,
    __hip_bfloat16* __restrict__ W0T_0, __hip_bfloat16* __restrict__ W0T_1)
{
    const int c = blockIdx.z;
    const float* s = rsv2 + (size_t)c * NPAD;
    __hip_bfloat16* W0T = c ? W0T_1 : W0T_0;
    const int f = blockIdx.y;
    const int k0 = (blockIdx.x * 256 + threadIdx.x) * 8;
    if (k0 >= NPAD) return;
    uint4 u = *reinterpret_cast<const uint4*>(&XT[(size_t)f * NPAD + k0]);
    const unsigned short* us = reinterpret_cast<const unsigned short*>(&u);
    __align__(16) __hip_bfloat16 h[8];
    #pragma unroll
    for (int e = 0; e < 8; ++e) {
        float x = __uint_as_float(((unsigned int)us[e]) << 16);
        h[e] = __float2bfloat16(x * s[k0 + e]);
    }
    *reinterpret_cast<uint4*>(&W0T[(size_t)f * NPAD + k0]) =
        *reinterpret_cast<const uint4*>(h);
}

// ---------------------------------------------------------------- batched panel GEMM (T-layout)
__global__ __launch_bounds__(256, 3) void gemm_pan_batch(
    const __hip_bfloat16* __restrict__ P0, const __hip_bfloat16* __restrict__ M0,
    const __hip_bfloat16* __restrict__ P1, const __hip_bfloat16* __restrict__ M1,
    const __hip_bfloat16* __restrict__ P2, const __hip_bfloat16* __restrict__ M2,
    __hip_bfloat16* __restrict__ part)
{
    const int b  = blockIdx.z / ZSPLIT;
    const int zz = blockIdx.z % ZSPLIT;
    const __hip_bfloat16* P = (b == 0) ? P0 : (b == 1) ? P1 : P2;
    const __hip_bfloat16* M = (b == 0) ? M0 : (b == 1) ? M1 : M2;
    __hip_bfloat16* C = part + (size_t)b * SLOT + (size_t)zz * PSTRIDE;

    __shared__ __align__(16) __hip_bfloat16 As[128 * 32];
    __shared__ __align__(16) __hip_bfloat16 Bs[128 * 32];
    const int t = threadIdx.x;
    const int lane = t & 63;
    const int w = t >> 6;
    const int wm = w >> 1, wn = w & 1;
    const int tn = blockIdx.x;
    const int kbeg = zz * KCHUNK;

    const int srow = lane >> 2;
    const int skg  = (lane & 3) * 8;
    const __hip_bfloat16* Ag = P + (size_t)(w * 32 + srow) * NPAD + skg;
    const __hip_bfloat16* Bg = M + (size_t)(tn * 128 + w * 32 + srow) * NPAD + skg;
    __hip_bfloat16* Al0 = &As[w * 1024];
    __hip_bfloat16* Al1 = &As[w * 1024 + 512];
    __hip_bfloat16* Bl0 = &Bs[w * 1024];
    __hip_bfloat16* Bl1 = &Bs[w * 1024 + 512];

    floatx4 acc[4][4] = {};

    for (int k0 = kbeg; k0 < kbeg + KCHUNK; k0 += 32) {
        __syncthreads();
        gload16(Ag + k0,             Al0);
        gload16(Ag + 16 * NPAD + k0, Al1);
        gload16(Bg + k0,             Bl0);
        gload16(Bg + 16 * NPAD + k0, Bl1);
        __syncthreads();

        bf16x8 af[4], bfv[4];
        const int koff = (lane >> 4) * 8;
        #pragma unroll
        for (int mi = 0; mi < 4; ++mi)
            af[mi] = *reinterpret_cast<const bf16x8*>(
                &As[(wm * 64 + mi * 16 + (lane & 15)) * 32 + koff]);
        #pragma unroll
        for (int ni = 0; ni < 4; ++ni)
            bfv[ni] = *reinterpret_cast<const bf16x8*>(
                &Bs[(wn * 64 + ni * 16 + (lane & 15)) * 32 + koff]);
        #pragma unroll
        for (int mi = 0; mi < 4; ++mi)
            #pragma unroll
            for (int ni = 0; ni < 4; ++ni)
                acc[mi][ni] = __builtin_amdgcn_mfma_f32_16x16x32_bf16(
                    af[mi], bfv[ni], acc[mi][ni], 0, 0, 0);
    }

    const int r0 = wm * 64 + ((lane >> 4) << 2);
    const int c0 = tn * 128 + wn * 64 + (lane & 15);
    #pragma unroll
    for (int mi = 0; mi < 4; ++mi)
        #pragma unroll
        for (int ni = 0; ni < 4; ++ni)
            #pragma unroll
            for (int r = 0; r < 4; ++r)
                C[(size_t)(r0 + mi * 16 + r) * NPAD + c0 + ni * 16] =
                    __float2bfloat16(acc[mi][ni][r]);
}

// ---------------------------------------------------------------- final GEMM (sigmoid epilogue)
__global__ __launch_bounds__(256, 3) void gemm_sig(
    const __hip_bfloat16* __restrict__ A, const __hip_bfloat16* __restrict__ BT,
    float* __restrict__ C, int Kchunk, int lda, int ldb, int ldc,
    int Mvalid, int Nvalid)
{
    __shared__ __align__(16) __hip_bfloat16 As[128 * 32];
    __shared__ __align__(16) __hip_bfloat16 Bs[128 * 32];
    const int t = threadIdx.x;
    const int lane = t & 63;
    const int w = t >> 6;
    const int wm = w >> 1, wn = w & 1;
    const int tm = blockIdx.y, tn = blockIdx.x;

    const int srow = lane >> 2;
    const int skg  = (lane & 3) * 8;
    const __hip_bfloat16* Ag = A  + (size_t)(tm * 128 + w * 32 + srow) * lda + skg;
    const __hip_bfloat16* Bg = BT + (size_t)(tn * 128 + w * 32 + srow) * ldb + skg;
    __hip_bfloat16* Al0 = &As[w * 1024];
    __hip_bfloat16* Al1 = &As[w * 1024 + 512];
    __hip_bfloat16* Bl0 = &Bs[w * 1024];
    __hip_bfloat16* Bl1 = &Bs[w * 1024 + 512];

    floatx4 acc[4][4] = {};

    for (int k0 = 0; k0 < Kchunk; k0 += 32) {
        __syncthreads();
        gload16(Ag + k0,            Al0);
        gload16(Ag + 16 * lda + k0, Al1);
        gload16(Bg + k0,            Bl0);
        gload16(Bg + 16 * ldb + k0, Bl1);
        __syncthreads();

        bf16x8 af[4], bfv[4];
        const int koff = (lane >> 4) * 8;
        #pragma unroll
        for (int mi = 0; mi < 4; ++mi)
            af[mi] = *reinterpret_cast<const bf16x8*>(
                &As[(wm * 64 + mi * 16 + (lane & 15)) * 32 + koff]);
        #pragma unroll
        for (int ni = 0; ni < 4; ++ni)
            bfv[ni] = *reinterpret_cast<const bf16x8*>(
                &Bs[(wn * 64 + ni * 16 + (lane & 15)) * 32 + koff]);
        #pragma unroll
        for (int mi = 0; mi < 4; ++mi)
            #pragma unroll
            for (int ni = 0; ni < 4; ++ni)
                acc[mi][ni] = __builtin_amdgcn_mfma_f32_16x16x32_bf16(
                    af[mi], bfv[ni], acc[mi][ni], 0, 0, 0);
    }

    const int r0 = tm * 128 + wm * 64 + ((lane >> 4) << 2);
    const int c0 = tn * 128 + wn * 64 + (lane & 15);
    #pragma unroll
    for (int mi = 0; mi < 4; ++mi)
        #pragma unroll
        for (int ni = 0; ni < 4; ++ni) {
            const int col = c0 + ni * 16;
            #pragma unroll
            for (int r = 0; r < 4; ++r) {
                const int row = r0 + mi * 16 + r;
                if (row < Mvalid && col < Nvalid)
                    C[(size_t)row * ldc + col] =
                        1.f / (1.f + __expf(-acc[mi][ni][r]));
            }
        }
}

// ---------------------------------------------------------------- elementwise z-sum of bf16 partials
__global__ __launch_bounds__(256) void reduce_sum_b(
    const __hip_bfloat16* __restrict__ part,
    __hip_bfloat16* __restrict__ O0, __hip_bfloat16* __restrict__ O1,
    __hip_bfloat16* __restrict__ O2)
{
    const int b = blockIdx.y;
    __hip_bfloat16* O = (b == 0) ? O0 : (b == 1) ? O1 : O2;
    if (!O) return;
    const __hip_bfloat16* Pp = part + (size_t)b * SLOT;
    const size_t idx = ((size_t)blockIdx.x * 256 + threadIdx.x) * 8;
    float s[8] = {};
    #pragma unroll
    for (int z = 0; z < ZSPLIT; ++z) {
        uint4 u = *reinterpret_cast<const uint4*>(&Pp[(size_t)z * PSTRIDE + idx]);
        const unsigned short* us = reinterpret_cast<const unsigned short*>(&u);
        #pragma unroll
        for (int e = 0; e < 8; ++e)
            s[e] += __uint_as_float(((unsigned int)us[e]) << 16);
    }
    __align__(16) __hip_bfloat16 h[8];
    #pragma unroll
    for (int e = 0; e < 8; ++e) h[e] = __float2bfloat16(s[e]);
    *reinterpret_cast<uint4*>(&O[idx]) = *reinterpret_cast<const uint4*>(h);
}

// ================================================================ R2 merged: DTI att write + U z-sums
// blocks [0,384): reduce_att_T (slot 0); [384,768): z-sum slots 1/2 -> U_0/U_1
__global__ __launch_bounds__(256) void reduce_s2(
    const __hip_bfloat16* __restrict__ part, const float* __restrict__ ap,
    float* __restrict__ conv,
    __hip_bfloat16* __restrict__ U0, __hip_bfloat16* __restrict__ U1)
{
    const int bid = blockIdx.x;
    const int t = threadIdx.x;
    if (bid < 384) {
        __shared__ float Ts[32][33];
        const int i0 = (bid % 96) * 32, f0 = (bid / 96) * 32;
        const int tr = t >> 5, tc = t & 31;
        float a0 = ap[0], a1 = ap[1], a2 = ap[2];
        float m = fmaxf(a0, fmaxf(a1, a2));
        float e0 = __expf(a0 - m), e1 = __expf(a1 - m), e2 = __expf(a2 - m);
        float att0 = e0 / (e0 + e1 + e2);
        #pragma unroll
        for (int p = 0; p < 4; ++p) {
            int f = f0 + tr + p * 8;
            float s = 0.f;
            #pragma unroll
            for (int z = 0; z < ZSPLIT; ++z)
                s += b2f(part[(size_t)z * PSTRIDE + (size_t)f * NPAD + i0 + tc]);
            Ts[tr + p * 8][tc] = s;
        }
        __syncthreads();
        #pragma unroll
        for (int p = 0; p < 4; ++p) {
            int i = i0 + tr + p * 8;
            conv[(size_t)i * 128 + f0 + tc] = att0 * Ts[tc][tr + p * 8];
        }
    } else {
        const int r = bid - 384;
        const int b = r / 192;                 // 0 or 1 -> slots 1/2
        __hip_bfloat16* O = b ? U1 : U0;
        const __hip_bfloat16* Pp = part + (size_t)(b + 1) * SLOT;
        const size_t idx = ((size_t)(r % 192) * 256 + t) * 8;
        float s[8] = {};
        #pragma unroll
        for (int z = 0; z < ZSPLIT; ++z) {
            uint4 u = *reinterpret_cast<const uint4*>(&Pp[(size_t)z * PSTRIDE + idx]);
            const unsigned short* us = reinterpret_cast<const unsigned short*>(&u);
            #pragma unroll
            for (int e = 0; e < 8; ++e)
                s[e] += __uint_as_float(((unsigned int)us[e]) << 16);
        }
        __align__(16) __hip_bfloat16 h[8];
        #pragma unroll
        for (int e = 0; e < 8; ++e) h[e] = __float2bfloat16(s[e]);
        *reinterpret_cast<uint4*>(&O[idx]) = *reinterpret_cast<const uint4*>(h);
    }
}

// ---------------------------------------------------------------- hop1 combine (elementwise, [f][i] layout)
__global__ __launch_bounds__(256) void combine_mid2(
    const __hip_bfloat16* __restrict__ part,
    const __hip_bfloat16* __restrict__ Z0, const __hip_bfloat16* __restrict__ Z1,
    const __hip_bfloat16* __restrict__ XTF,
    const float* __restrict__ rsv2, const float* __restrict__ dinv2,
    __hip_bfloat16* __restrict__ Wp0, __hip_bfloat16* __restrict__ Wp1)
{
    const int c = blockIdx.y;
    const __hip_bfloat16* Vp = part + (size_t)c * SLOT;
    const __hip_bfloat16* Z  = c ? Z1 : Z0;
    const float* sv = rsv2 + (size_t)c * NPAD;
    const float* dv = dinv2 + (size_t)c * NPAD;
    __hip_bfloat16* Wp = c ? Wp1 : Wp0;

    const size_t idx = ((size_t)blockIdx.x * 256 + threadIdx.x) * 8;
    const int i = (int)(idx % NPAD);
    float s[8] = {};
    #pragma unroll
    for (int z = 0; z < ZSPLIT; ++z) {
        uint4 u = *reinterpret_cast<const uint4*>(&Vp[(size_t)z * PSTRIDE + idx]);
        const unsigned short* us = reinterpret_cast<const unsigned short*>(&u);
        #pragma unroll
        for (int e = 0; e < 8; ++e)
            s[e] += __uint_as_float(((unsigned int)us[e]) << 16);
    }
    uint4 uz = *reinterpret_cast<const uint4*>(&Z[idx]);
    uint4 ux = *reinterpret_cast<const uint4*>(&XTF[idx]);
    const unsigned short* usz = reinterpret_cast<const unsigned short*>(&uz);
    const unsigned short* usx = reinterpret_cast<const unsigned short*>(&ux);
    __align__(16) __hip_bfloat16 h[8];
    #pragma unroll
    for (int e = 0; e < 8; ++e) {
        float vsum = s[e] + __uint_as_float(((unsigned int)usz[e]) << 16);
        float x    = __uint_as_float(((unsigned int)usx[e]) << 16);
        float si = sv[i + e], di = dv[i + e];
        float out1 = si * di * vsum + 2.f * si * si * x;
        h[e] = __float2bfloat16(si * out1);
    }
    *reinterpret_cast<uint4*>(&Wp[idx]) = *reinterpret_cast<const uint4*>(h);
}

// ================================================================ C2: hop2 combine + attention + split/cast
// writes dF/pF directly (replaces cast_split)
__global__ __launch_bounds__(256) void combine_att2_cast(
    const __hip_bfloat16* __restrict__ part,
    const __hip_bfloat16* __restrict__ Z2_0, const __hip_bfloat16* __restrict__ Z2_1,
    const __hip_bfloat16* __restrict__ Wp0, const __hip_bfloat16* __restrict__ Wp1,
    const float* __restrict__ rsv2, const float* __restrict__ dinv2,
    const float* __restrict__ ap, const float* __restrict__ conv,
    __hip_bfloat16* __restrict__ dF, __hip_bfloat16* __restrict__ pF)
{
    __shared__ float Ts[32][33];
    const int i0 = blockIdx.x * 32, f0 = blockIdx.y * 32;
    const int t = threadIdx.x, tr = t >> 5, tc = t & 31;
    float a0 = ap[0], a1 = ap[1], a2 = ap[2];
    float m = fmaxf(a0, fmaxf(a1, a2));
    float e0 = __expf(a0 - m), e1 = __expf(a1 - m), e2 = __expf(a2 - m);
    float inv = 1.f / (e0 + e1 + e2);
    float att1 = e1 * inv, att2 = e2 * inv;
    const int i = i0 + tc;
    float s0i = rsv2[i],        d0i = dinv2[i];
    float s1i = rsv2[NPAD + i], d1i = dinv2[NPAD + i];
    #pragma unroll
    for (int p = 0; p < 4; ++p) {
        int f = f0 + tr + p * 8;
        size_t fi = (size_t)f * NPAD + i;
        float v0 = b2f(Z2_0[fi]);
        float v1 = b2f(Z2_1[fi]);
        #pragma unroll
        for (int z = 0; z < ZSPLIT; ++z) {
            v0 += b2f(part[(size_t)z * PSTRIDE + fi]);
            v1 += b2f(part[SLOT + (size_t)z * PSTRIDE + fi]);
        }
        float o0 = s0i * d0i * v0 + 2.f * s0i * b2f(Wp0[fi]);
        float o1 = s1i * d1i * v1 + 2.f * s1i * b2f(Wp1[fi]);
        Ts[tr + p * 8][tc] = att1 * o0 + att2 * o1;
    }
    __syncthreads();
    #pragma unroll
    for (int p = 0; p < 4; ++p) {
        int i2 = i0 + tr + p * 8;
        int f = f0 + tc;
        float v = conv[(size_t)i2 * 128 + f] + Ts[tc][tr + p * 8];
        if (i2 < 1000) {
            dF[(size_t)i2 * 128 + f] = __float2bfloat16(v);
        } else {
            if (i2 < 1024) dF[(size_t)i2 * 128 + f] = __float2bfloat16(0.f);
            int pr = i2 - 1000;
            if (pr < 2048)
                pF[(size_t)pr * 128 + f] =
                    __float2bfloat16(i2 < NVALID ? v : 0.f);
        }
    }
}

// ================================================================ launch
extern "C" void kernel_launch(void* const* d_in, const int* in_sizes, int n_in,
                              void* d_out, int out_size, void* d_ws, size_t ws_size,
                              hipStream_t stream)
{
    const float* A     = (const float*)d_in[0];
    const float* DTI   = (const float*)d_in[1];
    const float* drugS = (const float*)d_in[2];
    const float* protS = (const float*)d_in[3];
    const float* w0a   = (const float*)d_in[4];
    const float* w0b   = (const float*)d_in[5];
    const float* w1g   = (const float*)d_in[6];
    const float* ap    = (const float*)d_in[7];
    const float* wd1 = (const float*)d_in[10]; const float* bd1 = (const float*)d_in[11];
    const float* wd2 = (const float*)d_in[12]; const float* bd2 = (const float*)d_in[13];
    const float* wd3 = (const float*)d_in[14]; const float* bd3 = (const float*)d_in[15];
    const float* wp1 = (const float*)d_in[16]; const float* bp1 = (const float*)d_in[17];
    const float* wp2 = (const float*)d_in[18]; const float* bp2 = (const float*)d_in[19];
    const float* wp3 = (const float*)d_in[20]; const float* bp3 = (const float*)d_in[21];
    float* out = (float*)d_out;

    const size_t SQ_BF  = (size_t)NPAD * NPAD * 2;
    const size_t PAN_BF = (size_t)128 * NPAD * 2;
    char* p = (char*)d_ws;
    auto alloc = [&](size_t sz) { char* r = p; p += (sz + 255) & ~(size_t)255; return r; };
    __hip_bfloat16* sdti = (__hip_bfloat16*)alloc(SQ_BF);
    __hip_bfloat16* a0c[2], *b0c[2], *g1c[2];
    for (int c = 0; c < 2; ++c) {
        a0c[c] = (__hip_bfloat16*)alloc(SQ_BF);
        b0c[c] = (__hip_bfloat16*)alloc(SQ_BF);
        g1c[c] = (__hip_bfloat16*)alloc(SQ_BF);
    }
    __hip_bfloat16* part = (__hip_bfloat16*)alloc((size_t)3 * SLOT * 2);
    float* r1v   = (float*)alloc((size_t)4 * NPAD * 4);
    float* dinv2 = (float*)alloc((size_t)2 * NPAD * 4);
    float* mv12  = (float*)alloc((size_t)2 * NPAD * 4);
    float* rsv2  = (float*)alloc((size_t)2 * NPAD * 4);
    float* degv  = (float*)alloc((size_t)NPAD * 4);
    float* fb    = (float*)alloc((size_t)NPAD * 128 * 4);
    float* conv  = (float*)alloc((size_t)NPAD * 128 * 4);
    __hip_bfloat16* XTF  = (__hip_bfloat16*)alloc(PAN_BF);
    __hip_bfloat16* XT2  = (__hip_bfloat16*)alloc(PAN_BF);
    __hip_bfloat16* W0T_0 = (__hip_bfloat16*)alloc(PAN_BF);
    __hip_bfloat16* W0T_1 = (__hip_bfloat16*)alloc(PAN_BF);
    __hip_bfloat16* Z_0  = (__hip_bfloat16*)alloc(PAN_BF);
    __hip_bfloat16* Z_1  = (__hip_bfloat16*)alloc(PAN_BF);
    __hip_bfloat16* U_0  = (__hip_bfloat16*)alloc(PAN_BF);
    __hip_bfloat16* U_1  = (__hip_bfloat16*)alloc(PAN_BF);
    __hip_bfloat16* Wp_0 = (__hip_bfloat16*)alloc(PAN_BF);
    __hip_bfloat16* Wp_1 = (__hip_bfloat16*)alloc(PAN_BF);
    __hip_bfloat16* dF = (__hip_bfloat16*)alloc((size_t)1024 * 128 * 2);
    __hip_bfloat16* pF = (__hip_bfloat16*)alloc((size_t)2048 * 128 * 2);
    if ((size_t)(p - (char*)d_ws) > ws_size) return;  // fail loud if ws too small

    // ---- L0: gtconv | DTI rowdeg | MLP (independent)
    head_fused<<<2 * NPAD + 375, 384, 0, stream>>>(
        A, w0a, w0b, w1g,
        a0c[0], b0c[0], g1c[0], a0c[1], b0c[1], g1c[1], r1v,
        DTI, degv,
        drugS, protS, wd1, bd1, wd2, bd2, wd3, bd3,
        wp1, bp1, wp2, bp2, wp3, bp3, fb);

    // ---- L1: transpose_feat | DTI scale_cast | matvec_degA
    mid_fused<<<21888, 256, 0, stream>>>(
        fb, XTF, DTI, degv, sdti,
        a0c[0], a0c[1], b0c[0], b0c[1], r1v, dinv2, mv12);

    // ---- degree stage B, W0T
    matvec_degB<<<dim3(NPAD, 2), 256, 0, stream>>>(a0c[0], a0c[1], mv12, dinv2, r1v, rsv2);
    scale_colsT2<<<dim3(2, 128, 2), 256, 0, stream>>>(XTF, rsv2, W0T_0, W0T_1);

    // ---- S1: panels {XTF x sdti, W0T_0 x g1_0, W0T_1 x g1_1}
    gemm_pan_batch<<<dim3(24, 1, 3 * ZSPLIT), 256, 0, stream>>>(
        XTF, sdti, W0T_0, g1c[0], W0T_1, g1c[1], part);
    reduce_sum_b<<<dim3(192, 3), 256, 0, stream>>>(part, XT2, Z_0, Z_1);

    // ---- S2: {XT2 x sdti, Z_0 x b0_0, Z_1 x b0_1}; then merged DTI-att + U sums
    gemm_pan_batch<<<dim3(24, 1, 3 * ZSPLIT), 256, 0, stream>>>(
        XT2, sdti, Z_0, b0c[0], Z_1, b0c[1], part);
    reduce_s2<<<768, 256, 0, stream>>>(part, ap, conv, U_0, U_1);

    // ---- S3: {U_0 x a0_0, U_1 x a0_1}; hop1 combine -> Wp
    gemm_pan_batch<<<dim3(24, 1, 2 * ZSPLIT), 256, 0, stream>>>(
        U_0, a0c[0], U_1, a0c[1], nullptr, nullptr, part);
    combine_mid2<<<dim3(192, 2), 256, 0, stream>>>(part, Z_0, Z_1, XTF,
        rsv2, dinv2, Wp_0, Wp_1);

    // ---- S4..S6: hop2
    gemm_pan_batch<<<dim3(24, 1, 2 * ZSPLIT), 256, 0, stream>>>(
        Wp_0, g1c[0], Wp_1, g1c[1], nullptr, nullptr, part);
    reduce_sum_b<<<dim3(192, 2), 256, 0, stream>>>(part, Z_0, Z_1, nullptr);
    gemm_pan_batch<<<dim3(24, 1, 2 * ZSPLIT), 256, 0, stream>>>(
        Z_0, b0c[0], Z_1, b0c[1], nullptr, nullptr, part);
    reduce_sum_b<<<dim3(192, 2), 256, 0, stream>>>(part, U_0, U_1, nullptr);
    gemm_pan_batch<<<dim3(24, 1, 2 * ZSPLIT), 256, 0, stream>>>(
        U_0, a0c[0], U_1, a0c[1], nullptr, nullptr, part);
    combine_att2_cast<<<dim3(96, 4), 256, 0, stream>>>(part, Z_0, Z_1, Wp_0, Wp_1,
        rsv2, dinv2, ap, conv, dF, pF);

    // ---- final: sigmoid(drug @ prot^T)
    gemm_sig<<<dim3(16, 8), 256, 0, stream>>>(dF, pF, out, 128, 128, 128, 2000, 1000, 2000);
}